// Round 7
// baseline (591.055 us; speedup 1.0000x reference)
//
#include <hip/hip_runtime.h>
#include <math.h>

#define SB 512
#define NB 128
#define HD 64

typedef _Float16 h2 __attribute__((ext_vector_type(2)));
typedef _Float16 f16x8 __attribute__((ext_vector_type(8)));
typedef float f32x4 __attribute__((ext_vector_type(4)));
union U4 { uint4 u; h2 h[4]; _Float16 f[8]; };
union UF { uint4 u; f16x8 h8; _Float16 f[8]; };
union U2 { uint2 u; _Float16 f[4]; };
union UH { unsigned u; _Float16 f[2]; };

__device__ __forceinline__ float frcp(float x) { return __builtin_amdgcn_rcpf(x); }
__device__ __forceinline__ float fsig(float x) { return frcp(1.0f + __expf(-x)); }
__device__ __forceinline__ float ftanh(float x) {
    float t = __expf(-2.0f * fabsf(x));
    float r = (1.0f - t) * frcp(1.0f + t);
    return copysignf(r, x);
}
__device__ __forceinline__ float fdot2(h2 a, h2 b, float c) {
    return __builtin_amdgcn_fdot2(a, b, c, false);
}

// ---------------------------------------------------------------------------
// prep: W2h (input-GEMM weights f16, K 100->104, round-0 layout), whhA (MFMA
// A-fragments, round-4-verified layout), bias2, Eexp = exp(trans).
// whhA dword index: [dir][R=16 rowtiles][kt=2][lane=64][j=4 dwords].
//   row m = lane&15 -> global row 16R+m = 4u+g (u = 4R+(m>>2), g = m&3);
//   frag k (dword j) = 32kt + 16(j>>1) + 4(lane>>4) + 2(j&1) + {0,1}.
// ---------------------------------------------------------------------------
__global__ void prep_kernel(const float* __restrict__ Wih_f, const float* __restrict__ Wih_bb,
                            const float* __restrict__ Whh_f, const float* __restrict__ Whh_bb,
                            const float* __restrict__ b_f, const float* __restrict__ b_bb,
                            const float* __restrict__ trans,
                            unsigned* __restrict__ W2h, unsigned* __restrict__ whhA,
                            float* __restrict__ bias2, float* __restrict__ Eexp)
{
    int idx = blockIdx.x * 256 + threadIdx.x;
    if (idx < 26624) {                       // W2h: [512 cols][52 half2-dwords]
        int col = idx / 52, d = idx - col * 52;
        int dir = col >> 8, r = col & 255, j = r >> 2, g = r & 3;
        const float* src = (dir ? Wih_bb : Wih_f) + (g * 64 + j) * 100;
        UH u; u.u = 0;
        if (d < 50) { u.f[0] = (_Float16)src[2 * d]; u.f[1] = (_Float16)src[2 * d + 1]; }
        W2h[idx] = u.u;
    } else if (idx < 43008) {                // whhA: 16384 dwords of A-fragments
        int d = idx - 26624;
        int j = d & 3, l = (d >> 2) & 63, kt = (d >> 8) & 1, R = (d >> 9) & 15, dir = (d >> 13) & 1;
        int m = l & 15;
        int u = 4 * R + (m >> 2), g = m & 3;
        int k = 32 * kt + 16 * (j >> 1) + ((l >> 4) << 2) + 2 * (j & 1);
        const float* src = (dir ? Whh_bb : Whh_f) + (g * 64 + u) * 64 + k;
        UH uu; uu.f[0] = (_Float16)src[0]; uu.f[1] = (_Float16)src[1];
        whhA[d] = uu.u;
    } else if (idx < 43520) {                // bias2
        int col = idx - 43008;
        int dir = col >> 8, r = col & 255, j = r >> 2, g = r & 3;
        bias2[col] = (dir ? b_bb : b_f)[g * 64 + j];
    } else if (idx < 43601) {                // Eexp = exp(trans), 81
        int i = idx - 43520;
        Eexp[i] = __expf(trans[i]);
    }
}

// ---------------------------------------------------------------------------
// input GEMM (f16 dot2, round-0 version): xgh[tb][512] = emb[token] . W2^T + b.
// (Round-6 MFMA variant regressed ~20us: fragment LDS reads had a constant
// bank across lanes -> 16-way conflict. Reverted.)
// ---------------------------------------------------------------------------
__global__ __launch_bounds__(256, 1) void gemm_kernel(
    const int* __restrict__ inputs, const float* __restrict__ emb,
    const unsigned* __restrict__ W2h, const float* __restrict__ bias2,
    _Float16* __restrict__ xgh)
{
    __shared__ __align__(16) unsigned sE[128 * 52];
    __shared__ __align__(16) unsigned sW[128 * 52];
    __shared__ int stok[128];
    const int tt = blockIdx.x;
    const int tid = threadIdx.x;

    if (tid < 128) stok[tid] = inputs[tid * SB + tt];
    __syncthreads();
    for (int idx = tid; idx < 6656; idx += 256) {
        int row = idx / 52, d = idx - row * 52;
        int token = stok[row];
        UH u; u.u = 0;
        if (d < 50) {
            const float* ep = emb + (size_t)token * 100 + 2 * d;
            u.f[0] = (_Float16)ep[0]; u.f[1] = (_Float16)ep[1];
        }
        sE[idx] = u.u;
    }

    const int tx = tid & 15, ty = tid >> 4;

    for (int cb4 = 0; cb4 < 4; ++cb4) {
        const int cb = cb4 * 128;
        __syncthreads();                    // protect sW from previous tile's readers
        for (int idx = tid; idx < 1664; idx += 256)
            ((uint4*)sW)[idx] = ((const uint4*)W2h)[cb * 13 + idx];
        __syncthreads();

        float acc[8][8];
        #pragma unroll
        for (int r = 0; r < 8; ++r)
            #pragma unroll
            for (int i = 0; i < 8; ++i) acc[r][i] = 0.f;

        for (int kk = 0; kk < 13; ++kk) {
            U4 e[8], wv[8];
            #pragma unroll
            for (int r = 0; r < 8; ++r) e[r].u = ((const uint4*)sE)[(ty + 16 * r) * 13 + kk];
            #pragma unroll
            for (int i = 0; i < 8; ++i) wv[i].u = ((const uint4*)sW)[(tx + 16 * i) * 13 + kk];
            #pragma unroll
            for (int r = 0; r < 8; ++r)
                #pragma unroll
                for (int i = 0; i < 8; ++i) {
                    float a = acc[r][i];
                    #pragma unroll
                    for (int q = 0; q < 4; ++q) a = fdot2(e[r].h[q], wv[i].h[q], a);
                    acc[r][i] = a;
                }
        }

        #pragma unroll
        for (int i = 0; i < 8; ++i) {
            int col = cb + tx + 16 * i;
            float bc = bias2[col];
            #pragma unroll
            for (int r = 0; r < 8; ++r) {
                int row = tt * NB + ty + 16 * r;
                xgh[(size_t)row * 512 + col] = (_Float16)(acc[r][i] + bc);
            }
        }
    }
}

// ---------------------------------------------------------------------------
// LSTM recurrence, single-wave MFMA: 256 blocks (b,dir) x 64 lanes (1 wave).
// Whh lives in 128 AGPRs as MFMA A-fragments (native operand read -- the only
// register class holding weights at zero per-step cost; rounds 1-2 proved VALU
// consumers pay accvgpr moves, rounds 4-5 proved MFMA A-frags are free).
// Per step: gates[256] = Whh @ h via 32 mfma_16x16x32_f16 (B = h broadcast,
// only col 0 used); D map (col=l&15,row=4(l>>4)+reg) + row order r=4u+g puts
// unit u's 4 gates in one lane's f32x4 -> 16 predicated b128 writes from the
// n==0 lanes, then ALL lanes read gbuf[j] (their unit) -- one b128. h -> hbuf
// (1 write) -> B-frags (4 b64 reads). 22 DS ops/step vs round-0's 41; no fdot2.
// No barriers: single wave, lgkmcnt orders all LDS RAW/WAR. x ring as round 0.
// ---------------------------------------------------------------------------
__global__ __attribute__((amdgpu_flat_work_group_size(64, 64), amdgpu_waves_per_eu(1, 1)))
void lstm_kernel(
    const _Float16* __restrict__ xgh, const unsigned* __restrict__ whhA,
    _Float16* __restrict__ h16)
{
    const int blk = blockIdx.x;
    const int b = blk & (NB - 1);
    const int dir = blk >> 7;
    const int j = threadIdx.x;          // lane; also unit id in activation phase
    const int q = j >> 4, n = j & 15;

    __shared__ __align__(16) float gbuf[64][4];     // [unit][gate] 1 KB
    __shared__ __align__(16) _Float16 hbuf[64];

    // A-fragments: 16 rowtiles x 2 ktiles = 128 dwords, AGPR-resident
    UF A[16][2];
    {
        const uint4* src = (const uint4*)whhA;
        #pragma unroll
        for (int R = 0; R < 16; ++R) {
            A[R][0].u = src[((dir * 16 + R) * 2 + 0) * 64 + j];
            A[R][1].u = src[((dir * 16 + R) * 2 + 1) * 64 + j];
        }
    }

    float c = 0.f;

    const int t0 = dir ? (SB - 1) : 0;
    const ptrdiff_t xstride = (dir ? -1 : 1) * (ptrdiff_t)(NB * 512);
    const _Float16* xp = xgh + ((size_t)(t0 * NB + b)) * 512 + dir * 256 + j * 4;
    _Float16* hp = h16 + ((size_t)(b * 2 + dir) * SB + t0) * 64 + j;
    const ptrdiff_t hstride = (dir ? -1 : 1) * (ptrdiff_t)64;

    U2 p0, p1, p2;
    p0.u = *(const uint2*)xp;
    p1.u = *(const uint2*)(xp + xstride);
    p2.u = *(const uint2*)(xp + 2 * xstride);
    const _Float16* xq = xp + 3 * xstride;

    UF B0, B1;                              // h(-1) = 0
    B0.u = make_uint4(0, 0, 0, 0);
    B1.u = make_uint4(0, 0, 0, 0);
    const f32x4 Z = {0.f, 0.f, 0.f, 0.f};

    for (int s = 0; s < SB; ++s) {
        // 32 MFMA: acc[R] = Whh[rows 16R..16R+15] @ h  (16 indep 2-chains)
        f32x4 acc[16];
        #pragma unroll
        for (int R = 0; R < 16; ++R) {
            acc[R] = __builtin_amdgcn_mfma_f32_16x16x32_f16(A[R][0].h8, B0.h8, Z, 0, 0, 0);
            acc[R] = __builtin_amdgcn_mfma_f32_16x16x32_f16(A[R][1].h8, B1.h8, acc[R], 0, 0, 0);
        }

        // x gate pre-activations (bias folded) from the prefetch ring
        float a0 = (float)p0.f[0], a1 = (float)p0.f[1];
        float a2 = (float)p0.f[2], a3 = (float)p0.f[3];
        p0 = p1; p1 = p2;
        p2.u = *(const uint2*)xq;           // 3-deep; overruns land in ws slack
        xq += xstride;

        // redistribute gates: col-0 lanes (n==0, q=0..3) own unit 4R+q
        if (n == 0) {
            #pragma unroll
            for (int R = 0; R < 16; ++R)
                *(float4*)&gbuf[4 * R + q][0] =
                    make_float4(acc[R][0], acc[R][1], acc[R][2], acc[R][3]);
        }
        float4 gg = *(const float4*)&gbuf[j][0];    // lgkm-ordered vs writes above
        a0 += gg.x; a1 += gg.y; a2 += gg.z; a3 += gg.w;

        float ig = fsig(a0), fg = fsig(a1), g_ = ftanh(a2), og = fsig(a3);
        c = fg * c + ig * g_;
        float h = og * ftanh(c);
        hbuf[j] = (_Float16)h;
        *hp = (_Float16)h;
        hp += hstride;

        // B-fragments for next step: k(dword j) = 32kt + 16(j>>1) + 4q + 2(j&1)
        {
            uint2 lo = *(const uint2*)&hbuf[4 * q];
            uint2 hi = *(const uint2*)&hbuf[16 + 4 * q];
            B0.u = make_uint4(lo.x, lo.y, hi.x, hi.y);
            lo = *(const uint2*)&hbuf[32 + 4 * q];
            hi = *(const uint2*)&hbuf[48 + 4 * q];
            B1.u = make_uint4(lo.x, lo.y, hi.x, hi.y);
        }
    }
}

// ---------------------------------------------------------------------------
// projection: block = batch b. h16 [b*2+dir][t][64] f16 staged in LDS per
// 128-t tile; em3[b][t*12+k] written coalesced per block.
// ---------------------------------------------------------------------------
__global__ __launch_bounds__(256, 1) void proj_kernel(
    const _Float16* __restrict__ h16, const float* __restrict__ W_out,
    const float* __restrict__ b_out, float* __restrict__ em3)
{
    __shared__ __align__(16) unsigned tile[128 * 64];   // [t][128 f16] = 32 KB
    __shared__ __align__(16) unsigned sWo[9 * 64];      // [k][128 f16]
    __shared__ float sb[9];
    const int b = blockIdx.x, tid = threadIdx.x;

    for (int i2 = tid; i2 < 576; i2 += 256) {
        int k = i2 >> 6, jp = i2 & 63;
        const float* src = W_out + (k + 1) * 128 + 2 * jp;
        UH u; u.f[0] = (_Float16)src[0]; u.f[1] = (_Float16)src[1];
        sWo[i2] = u.u;
    }
    if (tid < 9) sb[tid] = b_out[1 + tid];

    float* dst0 = em3 + (size_t)b * (SB * 12);

    for (int tt = 0; tt < 4; ++tt) {
        const int t0 = tt * 128;
        __syncthreads();
        #pragma unroll
        for (int dir = 0; dir < 2; ++dir) {
            const unsigned* src = (const unsigned*)(h16 + ((size_t)(b * 2 + dir) * SB + t0) * 64);
            for (int i = tid; i < 4096; i += 256) {
                int t = i >> 5, jp = i & 31;
                tile[t * 64 + dir * 32 + jp] = src[i];
            }
        }
        __syncthreads();

        for (int o = tid; o < 1152; o += 256) {
            int tl = o / 9, k = o - 9 * tl;
            const U4* hr = (const U4*)&tile[tl * 64];
            const U4* wr = (const U4*)&sWo[k * 64];
            float pa = 0.f, pb = 0.f;
            #pragma unroll
            for (int qq = 0; qq < 16; qq += 2) {
                U4 hv = hr[qq], wv = wr[qq];
                U4 hv2 = hr[qq + 1], wv2 = wr[qq + 1];
                #pragma unroll
                for (int z = 0; z < 4; ++z) {
                    pa = fdot2(hv.h[z], wv.h[z], pa);
                    pb = fdot2(hv2.h[z], wv2.h[z], pb);
                }
            }
            dst0[(t0 + tl) * 12 + k] = pa + pb + sb[k];
        }
    }
}

// ---------------------------------------------------------------------------
// CRF gold-path score: block = batch, 64 lanes strided over t, shuffle-reduce.
// ---------------------------------------------------------------------------
__global__ __launch_bounds__(64, 1) void crf_gold(
    const float* __restrict__ em3, const int* __restrict__ tags,
    const float* __restrict__ startv, const float* __restrict__ endv,
    const float* __restrict__ trans, float* __restrict__ gold)
{
    const int b = blockIdx.x, l = threadIdx.x;
    const int* tb = tags + (size_t)b * SB;
    const float* eb = em3 + (size_t)b * (SB * 12);
    float sc = 0.f;
    for (int t = l; t < SB; t += 64) {
        int tg = tb[t] - 1;
        if (t > 0) {
            int tp = tb[t - 1] - 1;
            sc += trans[tp * 9 + tg] + eb[t * 12 + tg];
        }
    }
    if (l == 0) {
        int tg0 = tb[0] - 1, tgl = tb[SB - 1] - 1;
        sc += startv[tg0] + eb[tg0] + endv[tgl];
    }
    #pragma unroll
    for (int off = 32; off > 0; off >>= 1) sc += __shfl_down(sc, off);
    if (l == 0) gold[b] = sc;
}

// ---------------------------------------------------------------------------
// CRF parallel scan: lane = (b, chunk); chunk c covers t in [1+16c, 1+16c+16).
// ---------------------------------------------------------------------------
__global__ __launch_bounds__(256, 1) void crf_scan(
    const float* __restrict__ em3, const float* __restrict__ Eexp,
    float* __restrict__ Pws)
{
    const int lane = blockIdx.x * 256 + threadIdx.x;   // 0..4095
    const int c = lane & 31, b = lane >> 5;

    float E[81];
    #pragma unroll
    for (int i = 0; i < 81; ++i) E[i] = Eexp[i];

    float P[81];
    #pragma unroll
    for (int i = 0; i < 81; ++i) P[i] = 0.f;
    #pragma unroll
    for (int i = 0; i < 9; ++i) P[i * 9 + i] = 1.f;
    float M = 0.f;

    const int t0 = 1 + 16 * c;
    const int nst = (t0 + 16 <= SB) ? 16 : (SB - t0);
    const float* ep = em3 + (size_t)b * (SB * 12) + t0 * 12;

    for (int s = 0; s < nst; ++s, ep += 12) {
        float4 e0 = *(const float4*)ep;
        float4 e1 = *(const float4*)(ep + 4);
        float e8 = ep[8];
        float ex[9] = { __expf(e0.x), __expf(e0.y), __expf(e0.z), __expf(e0.w),
                        __expf(e1.x), __expf(e1.y), __expf(e1.z), __expf(e1.w),
                        __expf(e8) };
        #pragma unroll
        for (int i = 0; i < 9; ++i) {
            float tmp[9];
            #pragma unroll
            for (int jj = 0; jj < 9; ++jj) tmp[jj] = P[i * 9] * E[jj];
            #pragma unroll
            for (int k = 1; k < 9; ++k)
                #pragma unroll
                for (int jj = 0; jj < 9; ++jj) tmp[jj] += P[i * 9 + k] * E[k * 9 + jj];
            #pragma unroll
            for (int jj = 0; jj < 9; ++jj) P[i * 9 + jj] = tmp[jj] * ex[jj];
        }
        if ((s & 3) == 3) {
            float mx = P[0];
            #pragma unroll
            for (int i = 1; i < 81; ++i) mx = fmaxf(mx, P[i]);
            M += __logf(mx);
            float r = frcp(mx);
            #pragma unroll
            for (int i = 0; i < 81; ++i) P[i] *= r;
        }
    }

    float* dst = Pws + (size_t)lane * 84;
    #pragma unroll
    for (int i = 0; i < 81; ++i) dst[i] = P[i];
    dst[81] = M;
}

// ---------------------------------------------------------------------------
// CRF combine: 128 lanes (b). alpha0 swept through 32 chunk matrices.
// ---------------------------------------------------------------------------
__global__ __launch_bounds__(128, 1) void crf_combine(
    const float* __restrict__ em3, const float* __restrict__ Pws,
    const float* __restrict__ gold, const float* __restrict__ startv,
    const float* __restrict__ endv, float* __restrict__ out)
{
    const int b = threadIdx.x;
    float A[9], M = 0.f;
    {
        const float* eb = em3 + (size_t)b * (SB * 12);
        float4 e0 = *(const float4*)eb;
        float4 e1 = *(const float4*)(eb + 4);
        float e[9] = { e0.x, e0.y, e0.z, e0.w, e1.x, e1.y, e1.z, e1.w, eb[8] };
        #pragma unroll
        for (int k = 0; k < 9; ++k) A[k] = __expf(startv[k] + e[k]);
    }

    for (int c = 0; c < 32; ++c) {
        const float4* src = (const float4*)(Pws + ((size_t)b * 32 + c) * 84);
        float buf[84];
        #pragma unroll
        for (int qq = 0; qq < 21; ++qq) {
            float4 v = src[qq];
            buf[4 * qq] = v.x; buf[4 * qq + 1] = v.y; buf[4 * qq + 2] = v.z; buf[4 * qq + 3] = v.w;
        }
        float tmp[9];
        #pragma unroll
        for (int jj = 0; jj < 9; ++jj) tmp[jj] = A[0] * buf[jj];
        #pragma unroll
        for (int i = 1; i < 9; ++i)
            #pragma unroll
            for (int jj = 0; jj < 9; ++jj) tmp[jj] += A[i] * buf[i * 9 + jj];
        float mx = tmp[0];
        #pragma unroll
        for (int jj = 1; jj < 9; ++jj) mx = fmaxf(mx, tmp[jj]);
        M += __logf(mx) + buf[81];
        float r = frcp(mx);
        #pragma unroll
        for (int jj = 0; jj < 9; ++jj) A[jj] = tmp[jj] * r;
    }

    float Z = 0.f;
    #pragma unroll
    for (int k = 0; k < 9; ++k) Z += A[k] * __expf(endv[k]);
    float part = M + __logf(Z) - gold[b];

    #pragma unroll
    for (int off = 32; off > 0; off >>= 1) part += __shfl_down(part, off);
    __shared__ float sm[2];
    if ((b & 63) == 0) sm[b >> 6] = part;
    __syncthreads();
    if (b == 0) out[0] = (sm[0] + sm[1]) * (1.0f / NB);
}

extern "C" void kernel_launch(void* const* d_in, const int* in_sizes, int n_in,
                              void* d_out, int out_size, void* d_ws, size_t ws_size,
                              hipStream_t stream)
{
    const int*   inputs = (const int*)d_in[0];
    const int*   tags   = (const int*)d_in[1];
    // d_in[2] = mask: all-true, unused
    const float* emb    = (const float*)d_in[3];
    const float* Wih_f  = (const float*)d_in[4];
    const float* Whh_f  = (const float*)d_in[5];
    const float* b_f    = (const float*)d_in[6];
    const float* Wih_b  = (const float*)d_in[7];
    const float* Whh_b  = (const float*)d_in[8];
    const float* b_b    = (const float*)d_in[9];
    const float* W_out  = (const float*)d_in[10];
    const float* b_out  = (const float*)d_in[11];
    const float* startv = (const float*)d_in[12];
    const float* endv   = (const float*)d_in[13];
    const float* transv = (const float*)d_in[14];

    char* w = (char*)d_ws;
    float* em3     = (float*)w;     w += (size_t)NB * SB * 12 * 4;    // 3.1 MB (pre-slack for dir=1 underrun)
    _Float16* xgh  = (_Float16*)w;  w += (size_t)SB * NB * 512 * 2;   // 67.1 MB
    _Float16* h16  = (_Float16*)w;  w += (size_t)NB * 2 * SB * 64 * 2;// 16.8 MB (post-slack for dir=0 overrun)
    float* Pws     = (float*)w;     w += (size_t)NB * 32 * 84 * 4;    // 1.4 MB
    float* gold    = (float*)w;     w += NB * 4;
    unsigned* W2h  = (unsigned*)w;  w += 26624 * 4;
    unsigned* whhA = (unsigned*)w;  w += 16384 * 4;
    float* bias2   = (float*)w;     w += 512 * 4;
    float* Eexp    = (float*)w;     w += 81 * 4;

    prep_kernel<<<171, 256, 0, stream>>>(Wih_f, Wih_b, Whh_f, Whh_b, b_f, b_b, transv,
                                         W2h, whhA, bias2, Eexp);
    gemm_kernel<<<SB, 256, 0, stream>>>(inputs, emb, W2h, bias2, xgh);
    lstm_kernel<<<256, 64, 0, stream>>>(xgh, whhA, h16);
    proj_kernel<<<NB, 256, 0, stream>>>(h16, W_out, b_out, em3);
    crf_gold<<<NB, 64, 0, stream>>>(em3, tags, startv, endv, transv, gold);
    crf_scan<<<16, 256, 0, stream>>>(em3, Eexp, Pws);
    crf_combine<<<1, 128, 0, stream>>>(em3, Pws, gold, startv, endv, (float*)d_out);
}

// Round 8
// 487.100 us; speedup vs baseline: 1.2134x; 1.2134x over previous
//
#include <hip/hip_runtime.h>
#include <math.h>

#define SB 512
#define NB 128
#define HD 64

typedef _Float16 h2 __attribute__((ext_vector_type(2)));
typedef _Float16 f16x8 __attribute__((ext_vector_type(8)));
typedef float f32x4 __attribute__((ext_vector_type(4)));
union U4 { uint4 u; h2 h[4]; _Float16 f[8]; };
union UF { uint4 u; f16x8 h8; _Float16 f[8]; };
union U2 { uint2 u; _Float16 f[4]; };
union UH { unsigned u; _Float16 f[2]; };

__device__ __forceinline__ float frcp(float x) { return __builtin_amdgcn_rcpf(x); }
__device__ __forceinline__ float fsig(float x) { return frcp(1.0f + __expf(-x)); }
__device__ __forceinline__ float ftanh(float x) {
    float t = __expf(-2.0f * fabsf(x));
    float r = (1.0f - t) * frcp(1.0f + t);
    return copysignf(r, x);
}
__device__ __forceinline__ float fdot2(h2 a, h2 b, float c) {
    return __builtin_amdgcn_fdot2(a, b, c, false);
}

// ---------------------------------------------------------------------------
// prep: W2h ([512 cols][64 dwords], k padded 100->128 with zeros, f16 pairs),
//       whh16 (LSTM LDS weights, round-0 layout), bias2, Eexp = exp(trans).
// W2h col = dir*256 + u*4 + g -> Wih row g*64+u.
// ---------------------------------------------------------------------------
__global__ void prep_kernel(const float* __restrict__ Wih_f, const float* __restrict__ Wih_bb,
                            const float* __restrict__ Whh_f, const float* __restrict__ Whh_bb,
                            const float* __restrict__ b_f, const float* __restrict__ b_bb,
                            const float* __restrict__ trans,
                            unsigned* __restrict__ W2h, unsigned* __restrict__ whh16,
                            float* __restrict__ bias2, float* __restrict__ Eexp)
{
    int idx = blockIdx.x * 256 + threadIdx.x;
    if (idx < 32768) {                       // W2h: [512 cols][64 dwords], zero-padded
        int col = idx >> 6, d = idx & 63;
        int dir = col >> 8, r = col & 255, j = r >> 2, g = r & 3;
        const float* src = (dir ? Wih_bb : Wih_f) + (g * 64 + j) * 100;
        UH u; u.u = 0;
        if (d < 50) { u.f[0] = (_Float16)src[2 * d]; u.f[1] = (_Float16)src[2 * d + 1]; }
        W2h[idx] = u.u;
    } else if (idx < 49152) {                // whh16: dword = ((dir*4+g)*8+k4)*256 + j*4 + q
        int d = idx - 32768;                 // 16384 dwords
        int kp = d & 31, u = (d >> 5) & 63, g = (d >> 11) & 3, dir = d >> 13;
        const float* src = (dir ? Whh_bb : Whh_f) + (g * 64 + u) * 64 + 2 * kp;
        UH uu; uu.f[0] = (_Float16)src[0]; uu.f[1] = (_Float16)src[1];
        int k4 = kp >> 2, q = kp & 3;
        whh16[(((dir * 4 + g) * 8 + k4) * 64 + u) * 4 + q] = uu.u;
    } else if (idx < 49664) {                // bias2
        int col = idx - 49152;
        int dir = col >> 8, r = col & 255, j = r >> 2, g = r & 3;
        bias2[col] = (dir ? b_bb : b_f)[g * 64 + j];
    } else if (idx < 49745) {                // Eexp = exp(trans), 81
        int i = idx - 49664;
        Eexp[i] = __expf(trans[i]);
    }
}

// ---------------------------------------------------------------------------
// input GEMM, MFMA, bank-fixed: xgh[(t*128+b)][512] = emb . W2^T + bias2.
// Round-6 MFMA version was numerically verified but had 16-way LDS conflicts
// (row stride 64 dwords -> bank constant across lanes). Rows now padded to
// 68 dwords: frag-read bank = (4n+2q+16kt)%32 -> 4-way (near b64 floor).
// Block = one t, 4 waves; wave w: row-tiles 2w,2w+1 x 8 col-tiles x 4 k-tiles
// = 256 mfma_f32_16x16x32_f16. Fragment maps HW-verified (rounds 4/5/6):
// A/B lane l: row/col = l&15, k(dword j) = 32kt+16(j>>1)+4(l>>4)+2(j&1);
// D: col = l&15, row = 4(l>>4)+reg.
// ---------------------------------------------------------------------------
__global__ __launch_bounds__(256, 2) void gemm_kernel(
    const int* __restrict__ inputs, const float* __restrict__ emb,
    const unsigned* __restrict__ W2h, const float* __restrict__ bias2,
    _Float16* __restrict__ xgh)
{
    __shared__ __align__(16) unsigned sE[128 * 68];   // 34.8 KB
    __shared__ __align__(16) unsigned sW[128 * 68];   // 34.8 KB
    __shared__ float sbias[512];
    __shared__ int stok[128];
    const int tt = blockIdx.x;
    const int tid = threadIdx.x;
    const int w = tid >> 6, l = tid & 63;
    const int q = l >> 4, n = l & 15;

    if (tid < 128) stok[tid] = inputs[tid * SB + tt];
    for (int i = tid; i < 512; i += 256) sbias[i] = bias2[i];
    __syncthreads();
    for (int idx = tid; idx < 8192; idx += 256) {
        int row = idx >> 6, d = idx & 63;
        unsigned v = 0;
        if (d < 50) {
            const float* ep = emb + (size_t)stok[row] * 100 + 2 * d;
            UH u; u.f[0] = (_Float16)ep[0]; u.f[1] = (_Float16)ep[1];
            v = u.u;
        }
        sE[row * 68 + d] = v;
    }

    for (int cg = 0; cg < 4; ++cg) {
        __syncthreads();                      // sE ready / sW safe to overwrite
        for (int idx = tid; idx < 2048; idx += 256)
            ((uint4*)sW)[(idx >> 4) * 17 + (idx & 15)] = ((const uint4*)W2h)[cg * 2048 + idx];
        __syncthreads();

        f32x4 acc[2][8];
        #pragma unroll
        for (int m = 0; m < 2; ++m)
            #pragma unroll
            for (int c = 0; c < 8; ++c)
                #pragma unroll
                for (int r = 0; r < 4; ++r) acc[m][c][r] = 0.f;

        #pragma unroll
        for (int kt = 0; kt < 4; ++kt) {
            const int ko = 16 * kt + 2 * q;
            UF A0, A1;
            {
                const unsigned* rp = &sE[(16 * (2 * w + 0) + n) * 68 + ko];
                uint2 lo = *(const uint2*)rp;
                uint2 hi = *(const uint2*)(rp + 8);
                A0.u = make_uint4(lo.x, lo.y, hi.x, hi.y);
                rp = &sE[(16 * (2 * w + 1) + n) * 68 + ko];
                lo = *(const uint2*)rp;
                hi = *(const uint2*)(rp + 8);
                A1.u = make_uint4(lo.x, lo.y, hi.x, hi.y);
            }
            UF B[8];
            #pragma unroll
            for (int c = 0; c < 8; ++c) {
                const unsigned* rp = &sW[(16 * c + n) * 68 + ko];
                uint2 lo = *(const uint2*)rp;
                uint2 hi = *(const uint2*)(rp + 8);
                B[c].u = make_uint4(lo.x, lo.y, hi.x, hi.y);
            }
            #pragma unroll
            for (int c = 0; c < 8; ++c) {
                acc[0][c] = __builtin_amdgcn_mfma_f32_16x16x32_f16(A0.h8, B[c].h8, acc[0][c], 0, 0, 0);
                acc[1][c] = __builtin_amdgcn_mfma_f32_16x16x32_f16(A1.h8, B[c].h8, acc[1][c], 0, 0, 0);
            }
        }

        #pragma unroll
        for (int m = 0; m < 2; ++m)
            #pragma unroll
            for (int c = 0; c < 8; ++c) {
                int col = cg * 128 + 16 * c + n;
                float bc = sbias[col];
                #pragma unroll
                for (int r = 0; r < 4; ++r) {
                    int row = 16 * (2 * w + m) + 4 * q + r;   // batch index
                    xgh[(size_t)(tt * NB + row) * 512 + col] = (_Float16)(acc[m][c][r] + bc);
                }
            }
    }
}

// ---------------------------------------------------------------------------
// LSTM recurrence: 256 blocks (b,dir) x 64 lanes (1 wave). Lane j = unit j.
// ROUND-0 STRUCTURE, FROZEN (best measured 218 us; every alternative tried --
// reg-pin, K-split 2-wave, MFMA 8/4-wave, single-wave MFMA -- regressed).
// ---------------------------------------------------------------------------
__global__ __attribute__((amdgpu_flat_work_group_size(64, 64), amdgpu_waves_per_eu(1, 1)))
void lstm_kernel(
    const _Float16* __restrict__ xgh, const unsigned* __restrict__ whh16,
    _Float16* __restrict__ h16)
{
    const int blk = blockIdx.x;
    const int b = blk & (NB - 1);
    const int dir = blk >> 7;
    const int j = threadIdx.x;

    __shared__ __align__(16) unsigned wlds[8192];   // 32 KB: [g][k4][j][q]
    __shared__ __align__(16) _Float16 hbuf[64];

    {   // stage dir-weights global -> LDS, coalesced (single wave, no barrier)
        const uint4* src = (const uint4*)(whh16 + dir * 8192);
        uint4* dst = (uint4*)wlds;
        #pragma unroll
        for (int i = 0; i < 32; ++i) dst[i * 64 + j] = src[i * 64 + j];
    }
    hbuf[j] = (_Float16)0.f;
    float c = 0.f;

    const int t0 = dir ? (SB - 1) : 0;
    const ptrdiff_t xstride = (dir ? -1 : 1) * (ptrdiff_t)(NB * 512);
    const _Float16* xp = xgh + ((size_t)(t0 * NB + b)) * 512 + dir * 256 + j * 4;
    _Float16* hp = h16 + ((size_t)(b * 2 + dir) * SB + t0) * 64 + j;
    const ptrdiff_t hstride = (dir ? -1 : 1) * (ptrdiff_t)64;

    U2 p0, p1, p2;
    p0.u = *(const uint2*)xp;
    p1.u = *(const uint2*)(xp + xstride);
    p2.u = *(const uint2*)(xp + 2 * xstride);
    const _Float16* xq = xp + 3 * xstride;

    const uint4* wl = (const uint4*)wlds;

    for (int s = 0; s < SB; ++s) {
        float a0 = (float)p0.f[0], a1 = (float)p0.f[1];
        float a2 = (float)p0.f[2], a3 = (float)p0.f[3];
        p0 = p1; p1 = p2;
        p2.u = *(const uint2*)xq;       // 3-deep; overruns land in adjacent ws slack
        xq += xstride;

        U4 hv[8];
        #pragma unroll
        for (int k4 = 0; k4 < 8; ++k4) hv[k4].u = *(const uint4*)&hbuf[k4 * 8];

        float g0[4] = {a0, 0.f, 0.f, 0.f};
        float g1[4] = {a1, 0.f, 0.f, 0.f};
        float g2[4] = {a2, 0.f, 0.f, 0.f};
        float g3[4] = {a3, 0.f, 0.f, 0.f};
        #pragma unroll
        for (int k4 = 0; k4 < 8; ++k4) {
            U4 w0, w1, w2, w3;
            w0.u = wl[(0 * 8 + k4) * 64 + j];
            w1.u = wl[(1 * 8 + k4) * 64 + j];
            w2.u = wl[(2 * 8 + k4) * 64 + j];
            w3.u = wl[(3 * 8 + k4) * 64 + j];
            const int p = k4 & 3;
            #pragma unroll
            for (int q = 0; q < 4; ++q) {
                g0[p] = fdot2(hv[k4].h[q], w0.h[q], g0[p]);
                g1[p] = fdot2(hv[k4].h[q], w1.h[q], g1[p]);
                g2[p] = fdot2(hv[k4].h[q], w2.h[q], g2[p]);
                g3[p] = fdot2(hv[k4].h[q], w3.h[q], g3[p]);
            }
        }
        a0 = (g0[0] + g0[1]) + (g0[2] + g0[3]);
        a1 = (g1[0] + g1[1]) + (g1[2] + g1[3]);
        a2 = (g2[0] + g2[1]) + (g2[2] + g2[3]);
        a3 = (g3[0] + g3[1]) + (g3[2] + g3[3]);

        float ig = fsig(a0), fg = fsig(a1), gg = ftanh(a2), og = fsig(a3);
        c = fg * c + ig * gg;
        float h = og * ftanh(c);
        *hp = (_Float16)h;
        hp += hstride;
        hbuf[j] = (_Float16)h;          // next iter's ds_reads ordered by lgkmcnt
    }
}

// ---------------------------------------------------------------------------
// FUSED projection + CRF gold + CRF scan: block = batch b, 256 threads.
// Phase 1: proj (4 x 128-t tiles) -> em3L in LDS (512x12 f32, 24.6 KB);
//          no em3 HBM round-trip. Phase 2 (overlapped): wave1 = gold score
//          (reads em3L), wave0 lanes 0..31 = 32 scan chunks (reads em3L),
//          tid 128..136 writes the t=0 row (em0) for crf_combine.
// ---------------------------------------------------------------------------
__global__ __launch_bounds__(256, 1) void pgs_kernel(
    const _Float16* __restrict__ h16, const float* __restrict__ W_out,
    const float* __restrict__ b_out, const int* __restrict__ tags,
    const float* __restrict__ startv, const float* __restrict__ endv,
    const float* __restrict__ trans, const float* __restrict__ Eexp,
    float* __restrict__ em0, float* __restrict__ gold, float* __restrict__ Pws)
{
    __shared__ __align__(16) unsigned tile[128 * 64];   // 32 KB staging
    __shared__ __align__(16) float em3L[SB * 12];       // 24.6 KB emissions
    __shared__ __align__(16) unsigned sWo[9 * 64];
    __shared__ float sb[9];
    const int b = blockIdx.x, tid = threadIdx.x;

    for (int i2 = tid; i2 < 576; i2 += 256) {
        int k = i2 >> 6, jp = i2 & 63;
        const float* src = W_out + (k + 1) * 128 + 2 * jp;
        UH u; u.f[0] = (_Float16)src[0]; u.f[1] = (_Float16)src[1];
        sWo[i2] = u.u;
    }
    if (tid < 9) sb[tid] = b_out[1 + tid];

    for (int tt = 0; tt < 4; ++tt) {
        const int t0 = tt * 128;
        __syncthreads();
        #pragma unroll
        for (int dir = 0; dir < 2; ++dir) {
            const unsigned* src = (const unsigned*)(h16 + ((size_t)(b * 2 + dir) * SB + t0) * 64);
            for (int i = tid; i < 4096; i += 256) {
                int t = i >> 5, jp = i & 31;
                tile[t * 64 + dir * 32 + jp] = src[i];
            }
        }
        __syncthreads();

        for (int o = tid; o < 1152; o += 256) {
            int tl = o / 9, k = o - 9 * tl;
            const U4* hr = (const U4*)&tile[tl * 64];
            const U4* wr = (const U4*)&sWo[k * 64];
            float pa = 0.f, pb = 0.f;
            #pragma unroll
            for (int qq = 0; qq < 16; qq += 2) {
                U4 hv = hr[qq], wv = wr[qq];
                U4 hv2 = hr[qq + 1], wv2 = wr[qq + 1];
                #pragma unroll
                for (int z = 0; z < 4; ++z) {
                    pa = fdot2(hv.h[z], wv.h[z], pa);
                    pb = fdot2(hv2.h[z], wv2.h[z], pb);
                }
            }
            em3L[(t0 + tl) * 12 + k] = pa + pb + sb[k];
        }
    }
    __syncthreads();    // em3L complete

    if (tid >= 128 && tid < 137)            // t=0 row for crf_combine
        em0[b * 12 + (tid - 128)] = em3L[tid - 128];

    if (tid >= 64 && tid < 128) {           // wave 1: gold-path score
        const int l = tid - 64;
        const int* tb = tags + (size_t)b * SB;
        float sc = 0.f;
        for (int t = l; t < SB; t += 64) {
            int tg = tb[t] - 1;
            if (t > 0) {
                int tp = tb[t - 1] - 1;
                sc += trans[tp * 9 + tg] + em3L[t * 12 + tg];
            }
        }
        if (l == 0) {
            int tg0 = tb[0] - 1, tgl = tb[SB - 1] - 1;
            sc += startv[tg0] + em3L[tg0] + endv[tgl];
        }
        #pragma unroll
        for (int off = 32; off > 0; off >>= 1) sc += __shfl_down(sc, off);
        if (l == 0) gold[b] = sc;
    }

    if (tid < 32) {                         // wave 0: 32 parallel scan chunks
        const int c = tid;
        float E[81];
        #pragma unroll
        for (int i = 0; i < 81; ++i) E[i] = Eexp[i];

        float P[81];
        #pragma unroll
        for (int i = 0; i < 81; ++i) P[i] = 0.f;
        #pragma unroll
        for (int i = 0; i < 9; ++i) P[i * 9 + i] = 1.f;
        float M = 0.f;

        const int t0 = 1 + 16 * c;
        const int nst = (t0 + 16 <= SB) ? 16 : (SB - t0);
        const float* ep = &em3L[t0 * 12];

        for (int s = 0; s < nst; ++s, ep += 12) {
            float4 e0 = *(const float4*)ep;
            float4 e1 = *(const float4*)(ep + 4);
            float e8 = ep[8];
            float ex[9] = { __expf(e0.x), __expf(e0.y), __expf(e0.z), __expf(e0.w),
                            __expf(e1.x), __expf(e1.y), __expf(e1.z), __expf(e1.w),
                            __expf(e8) };
            #pragma unroll
            for (int i = 0; i < 9; ++i) {
                float tmp[9];
                #pragma unroll
                for (int jj = 0; jj < 9; ++jj) tmp[jj] = P[i * 9] * E[jj];
                #pragma unroll
                for (int k = 1; k < 9; ++k)
                    #pragma unroll
                    for (int jj = 0; jj < 9; ++jj) tmp[jj] += P[i * 9 + k] * E[k * 9 + jj];
                #pragma unroll
                for (int jj = 0; jj < 9; ++jj) P[i * 9 + jj] = tmp[jj] * ex[jj];
            }
            if ((s & 3) == 3) {
                float mx = P[0];
                #pragma unroll
                for (int i = 1; i < 81; ++i) mx = fmaxf(mx, P[i]);
                M += __logf(mx);
                float r = frcp(mx);
                #pragma unroll
                for (int i = 0; i < 81; ++i) P[i] *= r;
            }
        }

        float* dst = Pws + ((size_t)b * 32 + c) * 84;
        #pragma unroll
        for (int i = 0; i < 81; ++i) dst[i] = P[i];
        dst[81] = M;
    }
}

// ---------------------------------------------------------------------------
// CRF combine: 128 lanes (b). alpha0 swept through 32 chunk matrices.
// em0[b*12 + 0..8] = emissions at t=0 (from pgs_kernel).
// ---------------------------------------------------------------------------
__global__ __launch_bounds__(128, 1) void crf_combine(
    const float* __restrict__ em0, const float* __restrict__ Pws,
    const float* __restrict__ gold, const float* __restrict__ startv,
    const float* __restrict__ endv, float* __restrict__ out)
{
    const int b = threadIdx.x;
    float A[9], M = 0.f;
    {
        const float* eb = em0 + (size_t)b * 12;
        float4 e0 = *(const float4*)eb;
        float4 e1 = *(const float4*)(eb + 4);
        float e[9] = { e0.x, e0.y, e0.z, e0.w, e1.x, e1.y, e1.z, e1.w, eb[8] };
        #pragma unroll
        for (int k = 0; k < 9; ++k) A[k] = __expf(startv[k] + e[k]);
    }

    for (int c = 0; c < 32; ++c) {
        const float4* src = (const float4*)(Pws + ((size_t)b * 32 + c) * 84);
        float buf[84];
        #pragma unroll
        for (int qq = 0; qq < 21; ++qq) {
            float4 v = src[qq];
            buf[4 * qq] = v.x; buf[4 * qq + 1] = v.y; buf[4 * qq + 2] = v.z; buf[4 * qq + 3] = v.w;
        }
        float tmp[9];
        #pragma unroll
        for (int jj = 0; jj < 9; ++jj) tmp[jj] = A[0] * buf[jj];
        #pragma unroll
        for (int i = 1; i < 9; ++i)
            #pragma unroll
            for (int jj = 0; jj < 9; ++jj) tmp[jj] += A[i] * buf[i * 9 + jj];
        float mx = tmp[0];
        #pragma unroll
        for (int jj = 1; jj < 9; ++jj) mx = fmaxf(mx, tmp[jj]);
        M += __logf(mx) + buf[81];
        float r = frcp(mx);
        #pragma unroll
        for (int jj = 0; jj < 9; ++jj) A[jj] = tmp[jj] * r;
    }

    float Z = 0.f;
    #pragma unroll
    for (int k = 0; k < 9; ++k) Z += A[k] * __expf(endv[k]);
    float part = M + __logf(Z) - gold[b];

    #pragma unroll
    for (int off = 32; off > 0; off >>= 1) part += __shfl_down(part, off);
    __shared__ float sm[2];
    if ((b & 63) == 0) sm[b >> 6] = part;
    __syncthreads();
    if (b == 0) out[0] = (sm[0] + sm[1]) * (1.0f / NB);
}

extern "C" void kernel_launch(void* const* d_in, const int* in_sizes, int n_in,
                              void* d_out, int out_size, void* d_ws, size_t ws_size,
                              hipStream_t stream)
{
    const int*   inputs = (const int*)d_in[0];
    const int*   tags   = (const int*)d_in[1];
    // d_in[2] = mask: all-true, unused
    const float* emb    = (const float*)d_in[3];
    const float* Wih_f  = (const float*)d_in[4];
    const float* Whh_f  = (const float*)d_in[5];
    const float* b_f    = (const float*)d_in[6];
    const float* Wih_b  = (const float*)d_in[7];
    const float* Whh_b  = (const float*)d_in[8];
    const float* b_b    = (const float*)d_in[9];
    const float* W_out  = (const float*)d_in[10];
    const float* b_out  = (const float*)d_in[11];
    const float* startv = (const float*)d_in[12];
    const float* endv   = (const float*)d_in[13];
    const float* transv = (const float*)d_in[14];

    char* w = (char*)d_ws;
    float* em0     = (float*)w;     w += (size_t)NB * SB * 12 * 4;    // 3.1 MB region: em0 uses 6 KB, rest = pre-slack for lstm dir=1 x-ring underrun
    _Float16* xgh  = (_Float16*)w;  w += (size_t)SB * NB * 512 * 2;   // 67.1 MB
    _Float16* h16  = (_Float16*)w;  w += (size_t)NB * 2 * SB * 64 * 2;// 16.8 MB (post-slack via Pws for dir=0 overrun)
    float* Pws     = (float*)w;     w += (size_t)NB * 32 * 84 * 4;    // 1.4 MB
    float* gold    = (float*)w;     w += NB * 4;
    unsigned* W2h  = (unsigned*)w;  w += 32768 * 4;
    unsigned* whh16= (unsigned*)w;  w += 16384 * 4;
    float* bias2   = (float*)w;     w += 512 * 4;
    float* Eexp    = (float*)w;     w += 81 * 4;

    prep_kernel<<<195, 256, 0, stream>>>(Wih_f, Wih_b, Whh_f, Whh_b, b_f, b_b, transv,
                                         W2h, whh16, bias2, Eexp);
    gemm_kernel<<<SB, 256, 0, stream>>>(inputs, emb, W2h, bias2, xgh);
    lstm_kernel<<<256, 64, 0, stream>>>(xgh, whh16, h16);
    pgs_kernel<<<NB, 256, 0, stream>>>(h16, W_out, b_out, tags, startv, endv, transv,
                                       Eexp, em0, gold, Pws);
    crf_combine<<<1, 128, 0, stream>>>(em0, Pws, gold, startv, endv, (float*)d_out);
}

// Round 9
// 452.660 us; speedup vs baseline: 1.3057x; 1.0761x over previous
//
#include <hip/hip_runtime.h>
#include <math.h>

#define SB 512
#define NB 128
#define HD 64

typedef _Float16 h2 __attribute__((ext_vector_type(2)));
typedef _Float16 f16x8 __attribute__((ext_vector_type(8)));
typedef float f32x4 __attribute__((ext_vector_type(4)));
union U4 { uint4 u; h2 h[4]; _Float16 f[8]; };
union UF { uint4 u; f16x8 h8; _Float16 f[8]; };
union U2 { uint2 u; _Float16 f[4]; };
union UH { unsigned u; _Float16 f[2]; };

__device__ __forceinline__ float frcp(float x) { return __builtin_amdgcn_rcpf(x); }
__device__ __forceinline__ float fsig(float x) { return frcp(1.0f + __expf(-x)); }
__device__ __forceinline__ float ftanh(float x) {
    float t = __expf(-2.0f * fabsf(x));
    float r = (1.0f - t) * frcp(1.0f + t);
    return copysignf(r, x);
}
__device__ __forceinline__ float fdot2(h2 a, h2 b, float c) {
    return __builtin_amdgcn_fdot2(a, b, c, false);
}

// ---------------------------------------------------------------------------
// input GEMM, MFMA, bank-fixed (round-8 verified): xgh = emb . W2^T + bias.
// prep_kernel eliminated: sW and sbias are converted on the fly from the raw
// Wih_f/Wih_b/b_f/b_b floats (L2-hot, 400 KB total across 512 blocks).
// col = dir*256 + u*4 + g -> Wih row g*64+u; K padded 100->128 with zeros.
// Rows padded to 68 dwords in LDS (4-way max bank aliasing on frag reads).
// Fragment maps HW-verified (rounds 4/5/6/8): A/B lane l: row/col = l&15,
// k(dword j) = 32kt+16(j>>1)+4(l>>4)+2(j&1); D: col = l&15, row = 4(l>>4)+reg.
// ---------------------------------------------------------------------------
__global__ __launch_bounds__(256, 2) void gemm_kernel(
    const int* __restrict__ inputs, const float* __restrict__ emb,
    const float* __restrict__ Wih_f, const float* __restrict__ Wih_bb,
    const float* __restrict__ b_f, const float* __restrict__ b_bb,
    _Float16* __restrict__ xgh)
{
    __shared__ __align__(16) unsigned sE[128 * 68];   // 34.8 KB
    __shared__ __align__(16) unsigned sW[128 * 68];   // 34.8 KB
    __shared__ float sbias[512];
    __shared__ int stok[128];
    const int tt = blockIdx.x;
    const int tid = threadIdx.x;
    const int w = tid >> 6, l = tid & 63;
    const int q = l >> 4, n = l & 15;

    if (tid < 128) stok[tid] = inputs[tid * SB + tt];
    for (int i = tid; i < 512; i += 256) {
        int dir = i >> 8, r = i & 255, jj = r >> 2, g = r & 3;
        sbias[i] = (dir ? b_bb : b_f)[g * 64 + jj];
    }
    __syncthreads();
    for (int idx = tid; idx < 8192; idx += 256) {
        int row = idx >> 6, d = idx & 63;
        unsigned v = 0;
        if (d < 50) {
            const float* ep = emb + (size_t)stok[row] * 100 + 2 * d;
            UH u; u.f[0] = (_Float16)ep[0]; u.f[1] = (_Float16)ep[1];
            v = u.u;
        }
        sE[row * 68 + d] = v;
    }

    for (int cg = 0; cg < 4; ++cg) {
        __syncthreads();                      // sE ready / sW safe to overwrite
        for (int idx = tid; idx < 2048; idx += 256) {
            int col = cg * 128 + (idx >> 4);
            int dir = col >> 8, r = col & 255, jj = r >> 2, g = r & 3;
            const float* base = (dir ? Wih_bb : Wih_f) + (g * 64 + jj) * 100;
            int dq = idx & 15;                // halves d = 4dq..4dq+3 = floats 8dq..8dq+7
            UF pack; pack.u = make_uint4(0, 0, 0, 0);
            if (dq < 12) {
                float4 f0 = *(const float4*)(base + 8 * dq);
                float4 f1 = *(const float4*)(base + 8 * dq + 4);
                pack.f[0] = (_Float16)f0.x; pack.f[1] = (_Float16)f0.y;
                pack.f[2] = (_Float16)f0.z; pack.f[3] = (_Float16)f0.w;
                pack.f[4] = (_Float16)f1.x; pack.f[5] = (_Float16)f1.y;
                pack.f[6] = (_Float16)f1.z; pack.f[7] = (_Float16)f1.w;
            } else if (dq == 12) {            // floats 96..99 valid, 100..103 pad
                float4 f0 = *(const float4*)(base + 96);
                pack.f[0] = (_Float16)f0.x; pack.f[1] = (_Float16)f0.y;
                pack.f[2] = (_Float16)f0.z; pack.f[3] = (_Float16)f0.w;
            }
            ((uint4*)sW)[(idx >> 4) * 17 + dq] = pack.u;
        }
        __syncthreads();

        f32x4 acc[2][8];
        #pragma unroll
        for (int m = 0; m < 2; ++m)
            #pragma unroll
            for (int c = 0; c < 8; ++c)
                #pragma unroll
                for (int r = 0; r < 4; ++r) acc[m][c][r] = 0.f;

        #pragma unroll
        for (int kt = 0; kt < 4; ++kt) {
            const int ko = 16 * kt + 2 * q;
            UF A0, A1;
            {
                const unsigned* rp = &sE[(16 * (2 * w + 0) + n) * 68 + ko];
                uint2 lo = *(const uint2*)rp;
                uint2 hi = *(const uint2*)(rp + 8);
                A0.u = make_uint4(lo.x, lo.y, hi.x, hi.y);
                rp = &sE[(16 * (2 * w + 1) + n) * 68 + ko];
                lo = *(const uint2*)rp;
                hi = *(const uint2*)(rp + 8);
                A1.u = make_uint4(lo.x, lo.y, hi.x, hi.y);
            }
            UF B[8];
            #pragma unroll
            for (int c = 0; c < 8; ++c) {
                const unsigned* rp = &sW[(16 * c + n) * 68 + ko];
                uint2 lo = *(const uint2*)rp;
                uint2 hi = *(const uint2*)(rp + 8);
                B[c].u = make_uint4(lo.x, lo.y, hi.x, hi.y);
            }
            #pragma unroll
            for (int c = 0; c < 8; ++c) {
                acc[0][c] = __builtin_amdgcn_mfma_f32_16x16x32_f16(A0.h8, B[c].h8, acc[0][c], 0, 0, 0);
                acc[1][c] = __builtin_amdgcn_mfma_f32_16x16x32_f16(A1.h8, B[c].h8, acc[1][c], 0, 0, 0);
            }
        }

        #pragma unroll
        for (int m = 0; m < 2; ++m)
            #pragma unroll
            for (int c = 0; c < 8; ++c) {
                int col = cg * 128 + 16 * c + n;
                float bc = sbias[col];
                #pragma unroll
                for (int r = 0; r < 4; ++r) {
                    int row = 16 * (2 * w + m) + 4 * q + r;   // batch index
                    xgh[(size_t)(tt * NB + row) * 512 + col] = (_Float16)(acc[m][c][r] + bc);
                }
            }
    }
}

// ---------------------------------------------------------------------------
// LSTM recurrence: 256 blocks (b,dir) x 64 lanes (1 wave). Lane j = unit j.
// ROUND-0 STRUCTURE, FROZEN (218 us; every alternative regressed). Change:
// wlds is converted on the fly from the raw Whh floats (prep eliminated);
// lane j loads 8 consecutive floats of row g*64+j per i -> same LDS layout
// [g][k4][j][q] as the old whh16 staging. One-time prologue ~1 us.
// ---------------------------------------------------------------------------
__global__ __attribute__((amdgpu_flat_work_group_size(64, 64), amdgpu_waves_per_eu(1, 1)))
void lstm_kernel(
    const _Float16* __restrict__ xgh, const float* __restrict__ Whh_f,
    const float* __restrict__ Whh_bb, _Float16* __restrict__ h16)
{
    const int blk = blockIdx.x;
    const int b = blk & (NB - 1);
    const int dir = blk >> 7;
    const int j = threadIdx.x;

    __shared__ __align__(16) unsigned wlds[8192];   // 32 KB: [g][k4][j][q]
    __shared__ __align__(16) _Float16 hbuf[64];

    {   // stage dir-weights global floats -> f16 LDS (single wave, no barrier)
        const float* Wsrc = dir ? Whh_bb : Whh_f;
        uint4* dst = (uint4*)wlds;
        #pragma unroll
        for (int i = 0; i < 32; ++i) {
            int g = i >> 3, k4 = i & 7;
            const float* rp = Wsrc + (g * 64 + j) * 64 + 8 * k4;
            float4 f0 = *(const float4*)rp;
            float4 f1 = *(const float4*)(rp + 4);
            UF pack;
            pack.f[0] = (_Float16)f0.x; pack.f[1] = (_Float16)f0.y;
            pack.f[2] = (_Float16)f0.z; pack.f[3] = (_Float16)f0.w;
            pack.f[4] = (_Float16)f1.x; pack.f[5] = (_Float16)f1.y;
            pack.f[6] = (_Float16)f1.z; pack.f[7] = (_Float16)f1.w;
            dst[i * 64 + j] = pack.u;
        }
    }
    hbuf[j] = (_Float16)0.f;
    float c = 0.f;

    const int t0 = dir ? (SB - 1) : 0;
    const ptrdiff_t xstride = (dir ? -1 : 1) * (ptrdiff_t)(NB * 512);
    const _Float16* xp = xgh + ((size_t)(t0 * NB + b)) * 512 + dir * 256 + j * 4;
    _Float16* hp = h16 + ((size_t)(b * 2 + dir) * SB + t0) * 64 + j;
    const ptrdiff_t hstride = (dir ? -1 : 1) * (ptrdiff_t)64;

    U2 p0, p1, p2;
    p0.u = *(const uint2*)xp;
    p1.u = *(const uint2*)(xp + xstride);
    p2.u = *(const uint2*)(xp + 2 * xstride);
    const _Float16* xq = xp + 3 * xstride;

    const uint4* wl = (const uint4*)wlds;

    for (int s = 0; s < SB; ++s) {
        float a0 = (float)p0.f[0], a1 = (float)p0.f[1];
        float a2 = (float)p0.f[2], a3 = (float)p0.f[3];
        p0 = p1; p1 = p2;
        p2.u = *(const uint2*)xq;       // 3-deep; overruns land in adjacent ws slack
        xq += xstride;

        U4 hv[8];
        #pragma unroll
        for (int k4 = 0; k4 < 8; ++k4) hv[k4].u = *(const uint4*)&hbuf[k4 * 8];

        float g0[4] = {a0, 0.f, 0.f, 0.f};
        float g1[4] = {a1, 0.f, 0.f, 0.f};
        float g2[4] = {a2, 0.f, 0.f, 0.f};
        float g3[4] = {a3, 0.f, 0.f, 0.f};
        #pragma unroll
        for (int k4 = 0; k4 < 8; ++k4) {
            U4 w0, w1, w2, w3;
            w0.u = wl[(0 * 8 + k4) * 64 + j];
            w1.u = wl[(1 * 8 + k4) * 64 + j];
            w2.u = wl[(2 * 8 + k4) * 64 + j];
            w3.u = wl[(3 * 8 + k4) * 64 + j];
            const int p = k4 & 3;
            #pragma unroll
            for (int q = 0; q < 4; ++q) {
                g0[p] = fdot2(hv[k4].h[q], w0.h[q], g0[p]);
                g1[p] = fdot2(hv[k4].h[q], w1.h[q], g1[p]);
                g2[p] = fdot2(hv[k4].h[q], w2.h[q], g2[p]);
                g3[p] = fdot2(hv[k4].h[q], w3.h[q], g3[p]);
            }
        }
        a0 = (g0[0] + g0[1]) + (g0[2] + g0[3]);
        a1 = (g1[0] + g1[1]) + (g1[2] + g1[3]);
        a2 = (g2[0] + g2[1]) + (g2[2] + g2[3]);
        a3 = (g3[0] + g3[1]) + (g3[2] + g3[3]);

        float ig = fsig(a0), fg = fsig(a1), gg = ftanh(a2), og = fsig(a3);
        c = fg * c + ig * gg;
        float h = og * ftanh(c);
        *hp = (_Float16)h;
        hp += hstride;
        hbuf[j] = (_Float16)h;          // next iter's ds_reads ordered by lgkmcnt
    }
}

// ---------------------------------------------------------------------------
// FUSED projection + CRF gold + scan + alpha-sweep: block = batch b, 256 thr.
// Phase 1: proj -> em3L in LDS (no HBM round-trip). Phase 2: wave1 = gold ->
// sgold (LDS); wave0 lanes 0..31 = 32 scan chunks -> chunk matrices written
// to Pst (aliases the proj staging tile, free after phase 1). Phase 3: wave0
// sweeps alpha through the 32 matrices ENTIRELY IN LDS (old crf_combine body,
// same order/renorm -> same rounding), emits one scalar parts[b].
// Pws/gold/em0 never touch HBM.
// ---------------------------------------------------------------------------
__global__ __launch_bounds__(256, 1) void pgs_kernel(
    const _Float16* __restrict__ h16, const float* __restrict__ W_out,
    const float* __restrict__ b_out, const int* __restrict__ tags,
    const float* __restrict__ startv, const float* __restrict__ endv,
    const float* __restrict__ trans, float* __restrict__ parts)
{
    __shared__ __align__(16) unsigned tile[128 * 64];   // 32 KB staging; phase-3 alias: Pst
    __shared__ __align__(16) float em3L[SB * 12];       // 24.6 KB emissions
    __shared__ __align__(16) unsigned sWo[9 * 64];
    __shared__ float sb[9];
    __shared__ float sEexp[81];
    __shared__ float sgold;
    const int b = blockIdx.x, tid = threadIdx.x;
    float* Pst = (float*)tile;                          // [32][84]

    for (int i2 = tid; i2 < 576; i2 += 256) {
        int k = i2 >> 6, jp = i2 & 63;
        const float* src = W_out + (k + 1) * 128 + 2 * jp;
        UH u; u.f[0] = (_Float16)src[0]; u.f[1] = (_Float16)src[1];
        sWo[i2] = u.u;
    }
    if (tid < 9) sb[tid] = b_out[1 + tid];
    if (tid < 81) sEexp[tid] = __expf(trans[tid]);

    for (int tt = 0; tt < 4; ++tt) {
        const int t0 = tt * 128;
        __syncthreads();
        #pragma unroll
        for (int dir = 0; dir < 2; ++dir) {
            const unsigned* src = (const unsigned*)(h16 + ((size_t)(b * 2 + dir) * SB + t0) * 64);
            for (int i = tid; i < 4096; i += 256) {
                int t = i >> 5, jp = i & 31;
                tile[t * 64 + dir * 32 + jp] = src[i];
            }
        }
        __syncthreads();

        for (int o = tid; o < 1152; o += 256) {
            int tl = o / 9, k = o - 9 * tl;
            const U4* hr = (const U4*)&tile[tl * 64];
            const U4* wr = (const U4*)&sWo[k * 64];
            float pa = 0.f, pb = 0.f;
            #pragma unroll
            for (int qq = 0; qq < 16; qq += 2) {
                U4 hv = hr[qq], wv = wr[qq];
                U4 hv2 = hr[qq + 1], wv2 = wr[qq + 1];
                #pragma unroll
                for (int z = 0; z < 4; ++z) {
                    pa = fdot2(hv.h[z], wv.h[z], pa);
                    pb = fdot2(hv2.h[z], wv2.h[z], pb);
                }
            }
            em3L[(t0 + tl) * 12 + k] = pa + pb + sb[k];
        }
    }
    __syncthreads();    // em3L complete; tile free from here (Pst alias)

    if (tid >= 64 && tid < 128) {           // wave 1: gold-path score -> sgold
        const int l = tid - 64;
        const int* tb = tags + (size_t)b * SB;
        float sc = 0.f;
        for (int t = l; t < SB; t += 64) {
            int tg = tb[t] - 1;
            if (t > 0) {
                int tp = tb[t - 1] - 1;
                sc += trans[tp * 9 + tg] + em3L[t * 12 + tg];
            }
        }
        if (l == 0) {
            int tg0 = tb[0] - 1, tgl = tb[SB - 1] - 1;
            sc += startv[tg0] + em3L[tg0] + endv[tgl];
        }
        #pragma unroll
        for (int off = 32; off > 0; off >>= 1) sc += __shfl_down(sc, off);
        if (l == 0) sgold = sc;
    }

    if (tid < 32) {                         // wave 0: 32 parallel scan chunks -> Pst
        const int c = tid;
        float E[81];
        #pragma unroll
        for (int i = 0; i < 81; ++i) E[i] = sEexp[i];

        float P[81];
        #pragma unroll
        for (int i = 0; i < 81; ++i) P[i] = 0.f;
        #pragma unroll
        for (int i = 0; i < 9; ++i) P[i * 9 + i] = 1.f;
        float M = 0.f;

        const int t0 = 1 + 16 * c;
        const int nst = (t0 + 16 <= SB) ? 16 : (SB - t0);
        const float* ep = &em3L[t0 * 12];

        for (int s = 0; s < nst; ++s, ep += 12) {
            float4 e0 = *(const float4*)ep;
            float4 e1 = *(const float4*)(ep + 4);
            float e8 = ep[8];
            float ex[9] = { __expf(e0.x), __expf(e0.y), __expf(e0.z), __expf(e0.w),
                            __expf(e1.x), __expf(e1.y), __expf(e1.z), __expf(e1.w),
                            __expf(e8) };
            #pragma unroll
            for (int i = 0; i < 9; ++i) {
                float tmp[9];
                #pragma unroll
                for (int jj = 0; jj < 9; ++jj) tmp[jj] = P[i * 9] * E[jj];
                #pragma unroll
                for (int k = 1; k < 9; ++k)
                    #pragma unroll
                    for (int jj = 0; jj < 9; ++jj) tmp[jj] += P[i * 9 + k] * E[k * 9 + jj];
                #pragma unroll
                for (int jj = 0; jj < 9; ++jj) P[i * 9 + jj] = tmp[jj] * ex[jj];
            }
            if ((s & 3) == 3) {
                float mx = P[0];
                #pragma unroll
                for (int i = 1; i < 81; ++i) mx = fmaxf(mx, P[i]);
                M += __logf(mx);
                float r = frcp(mx);
                #pragma unroll
                for (int i = 0; i < 81; ++i) P[i] *= r;
            }
        }

        float* dst = &Pst[c * 84];
        #pragma unroll
        for (int i = 0; i < 81; ++i) dst[i] = P[i];
        dst[81] = M;
    }
    __syncthreads();    // Pst + sgold ready

    if (tid < 64) {                         // wave 0 (redundant lanes): alpha sweep in LDS
        float A[9], M = 0.f;
        #pragma unroll
        for (int k = 0; k < 9; ++k) A[k] = __expf(startv[k] + em3L[k]);

        for (int c = 0; c < 32; ++c) {
            const float4* src = (const float4*)&Pst[c * 84];
            float buf[84];
            #pragma unroll
            for (int qq = 0; qq < 21; ++qq) {
                float4 v = src[qq];
                buf[4 * qq] = v.x; buf[4 * qq + 1] = v.y; buf[4 * qq + 2] = v.z; buf[4 * qq + 3] = v.w;
            }
            float tmp[9];
            #pragma unroll
            for (int jj = 0; jj < 9; ++jj) tmp[jj] = A[0] * buf[jj];
            #pragma unroll
            for (int i = 1; i < 9; ++i)
                #pragma unroll
                for (int jj = 0; jj < 9; ++jj) tmp[jj] += A[i] * buf[i * 9 + jj];
            float mx = tmp[0];
            #pragma unroll
            for (int jj = 1; jj < 9; ++jj) mx = fmaxf(mx, tmp[jj]);
            M += __logf(mx) + buf[81];
            float r = frcp(mx);
            #pragma unroll
            for (int jj = 0; jj < 9; ++jj) A[jj] = tmp[jj] * r;
        }

        float Z = 0.f;
        #pragma unroll
        for (int k = 0; k < 9; ++k) Z += A[k] * __expf(endv[k]);
        float part = M + __logf(Z) - sgold;
        if (tid == 0) parts[b] = part;
    }
}

// ---------------------------------------------------------------------------
// final reduce: 128 lanes, same tree order as the original combine.
// ---------------------------------------------------------------------------
__global__ __launch_bounds__(128, 1) void crf_combine2(
    const float* __restrict__ parts, float* __restrict__ out)
{
    const int b = threadIdx.x;
    float part = parts[b];
    #pragma unroll
    for (int off = 32; off > 0; off >>= 1) part += __shfl_down(part, off);
    __shared__ float sm[2];
    if ((b & 63) == 0) sm[b >> 6] = part;
    __syncthreads();
    if (b == 0) out[0] = (sm[0] + sm[1]) * (1.0f / NB);
}

extern "C" void kernel_launch(void* const* d_in, const int* in_sizes, int n_in,
                              void* d_out, int out_size, void* d_ws, size_t ws_size,
                              hipStream_t stream)
{
    const int*   inputs = (const int*)d_in[0];
    const int*   tags   = (const int*)d_in[1];
    // d_in[2] = mask: all-true, unused
    const float* emb    = (const float*)d_in[3];
    const float* Wih_f  = (const float*)d_in[4];
    const float* Whh_f  = (const float*)d_in[5];
    const float* b_f    = (const float*)d_in[6];
    const float* Wih_b  = (const float*)d_in[7];
    const float* Whh_b  = (const float*)d_in[8];
    const float* b_b    = (const float*)d_in[9];
    const float* W_out  = (const float*)d_in[10];
    const float* b_out  = (const float*)d_in[11];
    const float* startv = (const float*)d_in[12];
    const float* endv   = (const float*)d_in[13];
    const float* transv = (const float*)d_in[14];

    char* w = (char*)d_ws;
    float* parts   = (float*)w;     w += (size_t)NB * SB * 12 * 4;    // 3.1 MB region: parts uses 512 B,
                                                                      // rest = pre-slack for lstm dir=1 x-ring underrun (<=768 KB)
    _Float16* xgh  = (_Float16*)w;  w += (size_t)SB * NB * 512 * 2;   // 67.1 MB
    _Float16* h16  = (_Float16*)w;  w += (size_t)NB * 2 * SB * 64 * 2;// 16.8 MB (post-slack for dir=0 x-ring overrun)
    (void)w;

    gemm_kernel<<<SB, 256, 0, stream>>>(inputs, emb, Wih_f, Wih_b, b_f, b_b, xgh);
    lstm_kernel<<<256, 64, 0, stream>>>(xgh, Whh_f, Whh_b, h16);
    pgs_kernel<<<NB, 256, 0, stream>>>(h16, W_out, b_out, tags, startv, endv, transv, parts);
    crf_combine2<<<1, 128, 0, stream>>>(parts, (float*)d_out);
}

// Round 10
// 449.690 us; speedup vs baseline: 1.3144x; 1.0066x over previous
//
#include <hip/hip_runtime.h>
#include <math.h>

#define SB 512
#define NB 128
#define HD 64

typedef _Float16 h2 __attribute__((ext_vector_type(2)));
typedef _Float16 f16x8 __attribute__((ext_vector_type(8)));
typedef float f32x4 __attribute__((ext_vector_type(4)));
union U4 { uint4 u; h2 h[4]; _Float16 f[8]; };
union UF { uint4 u; f16x8 h8; _Float16 f[8]; };
union U2 { uint2 u; _Float16 f[4]; };
union UH { unsigned u; _Float16 f[2]; };

__device__ __forceinline__ float frcp(float x) { return __builtin_amdgcn_rcpf(x); }
__device__ __forceinline__ float fsig(float x) { return frcp(1.0f + __expf(-x)); }
__device__ __forceinline__ float ftanh(float x) {
    float t = __expf(-2.0f * fabsf(x));
    float r = (1.0f - t) * frcp(1.0f + t);
    return copysignf(r, x);
}
__device__ __forceinline__ float fdot2(h2 a, h2 b, float c) {
    return __builtin_amdgcn_fdot2(a, b, c, false);
}

// ---------------------------------------------------------------------------
// input GEMM, MFMA, bank-fixed (rounds 8/9 verified, unchanged except cnt=0
// init for the megakernel's last-block-done protocol).
// ---------------------------------------------------------------------------
__global__ __launch_bounds__(256, 2) void gemm_kernel(
    const int* __restrict__ inputs, const float* __restrict__ emb,
    const float* __restrict__ Wih_f, const float* __restrict__ Wih_bb,
    const float* __restrict__ b_f, const float* __restrict__ b_bb,
    _Float16* __restrict__ xgh, unsigned* __restrict__ cnt)
{
    __shared__ __align__(16) unsigned sE[128 * 68];   // 34.8 KB
    __shared__ __align__(16) unsigned sW[128 * 68];   // 34.8 KB
    __shared__ float sbias[512];
    __shared__ int stok[128];
    const int tt = blockIdx.x;
    const int tid = threadIdx.x;
    const int w = tid >> 6, l = tid & 63;
    const int q = l >> 4, n = l & 15;

    if (tt == 0 && tid == 0) *cnt = 0u;   // reset last-block counter each replay

    if (tid < 128) stok[tid] = inputs[tid * SB + tt];
    for (int i = tid; i < 512; i += 256) {
        int dir = i >> 8, r = i & 255, jj = r >> 2, g = r & 3;
        sbias[i] = (dir ? b_bb : b_f)[g * 64 + jj];
    }
    __syncthreads();
    for (int idx = tid; idx < 8192; idx += 256) {
        int row = idx >> 6, d = idx & 63;
        unsigned v = 0;
        if (d < 50) {
            const float* ep = emb + (size_t)stok[row] * 100 + 2 * d;
            UH u; u.f[0] = (_Float16)ep[0]; u.f[1] = (_Float16)ep[1];
            v = u.u;
        }
        sE[row * 68 + d] = v;
    }

    for (int cg = 0; cg < 4; ++cg) {
        __syncthreads();                      // sE ready / sW safe to overwrite
        for (int idx = tid; idx < 2048; idx += 256) {
            int col = cg * 128 + (idx >> 4);
            int dir = col >> 8, r = col & 255, jj = r >> 2, g = r & 3;
            const float* base = (dir ? Wih_bb : Wih_f) + (g * 64 + jj) * 100;
            int dq = idx & 15;                // halves d = 4dq..4dq+3 = floats 8dq..8dq+7
            UF pack; pack.u = make_uint4(0, 0, 0, 0);
            if (dq < 12) {
                float4 f0 = *(const float4*)(base + 8 * dq);
                float4 f1 = *(const float4*)(base + 8 * dq + 4);
                pack.f[0] = (_Float16)f0.x; pack.f[1] = (_Float16)f0.y;
                pack.f[2] = (_Float16)f0.z; pack.f[3] = (_Float16)f0.w;
                pack.f[4] = (_Float16)f1.x; pack.f[5] = (_Float16)f1.y;
                pack.f[6] = (_Float16)f1.z; pack.f[7] = (_Float16)f1.w;
            } else if (dq == 12) {            // floats 96..99 valid, 100..103 pad
                float4 f0 = *(const float4*)(base + 96);
                pack.f[0] = (_Float16)f0.x; pack.f[1] = (_Float16)f0.y;
                pack.f[2] = (_Float16)f0.z; pack.f[3] = (_Float16)f0.w;
            }
            ((uint4*)sW)[(idx >> 4) * 17 + dq] = pack.u;
        }
        __syncthreads();

        f32x4 acc[2][8];
        #pragma unroll
        for (int m = 0; m < 2; ++m)
            #pragma unroll
            for (int c = 0; c < 8; ++c)
                #pragma unroll
                for (int r = 0; r < 4; ++r) acc[m][c][r] = 0.f;

        #pragma unroll
        for (int kt = 0; kt < 4; ++kt) {
            const int ko = 16 * kt + 2 * q;
            UF A0, A1;
            {
                const unsigned* rp = &sE[(16 * (2 * w + 0) + n) * 68 + ko];
                uint2 lo = *(const uint2*)rp;
                uint2 hi = *(const uint2*)(rp + 8);
                A0.u = make_uint4(lo.x, lo.y, hi.x, hi.y);
                rp = &sE[(16 * (2 * w + 1) + n) * 68 + ko];
                lo = *(const uint2*)rp;
                hi = *(const uint2*)(rp + 8);
                A1.u = make_uint4(lo.x, lo.y, hi.x, hi.y);
            }
            UF B[8];
            #pragma unroll
            for (int c = 0; c < 8; ++c) {
                const unsigned* rp = &sW[(16 * c + n) * 68 + ko];
                uint2 lo = *(const uint2*)rp;
                uint2 hi = *(const uint2*)(rp + 8);
                B[c].u = make_uint4(lo.x, lo.y, hi.x, hi.y);
            }
            #pragma unroll
            for (int c = 0; c < 8; ++c) {
                acc[0][c] = __builtin_amdgcn_mfma_f32_16x16x32_f16(A0.h8, B[c].h8, acc[0][c], 0, 0, 0);
                acc[1][c] = __builtin_amdgcn_mfma_f32_16x16x32_f16(A1.h8, B[c].h8, acc[1][c], 0, 0, 0);
            }
        }

        #pragma unroll
        for (int m = 0; m < 2; ++m)
            #pragma unroll
            for (int c = 0; c < 8; ++c) {
                int col = cg * 128 + 16 * c + n;
                float bc = sbias[col];
                #pragma unroll
                for (int r = 0; r < 4; ++r) {
                    int row = 16 * (2 * w + m) + 4 * q + r;   // batch index
                    xgh[(size_t)(tt * NB + row) * 512 + col] = (_Float16)(acc[m][c][r] + bc);
                }
            }
    }
}

// ---------------------------------------------------------------------------
// MEGAKERNEL: lstm + proj + gold + scan + alpha + final reduce. 128 blocks
// (= batch b) x 256 threads.
// Phase 1: waves 0/1 run the FROZEN round-0 single-wave recurrence for
//   dir 0/1 (private wlds half in `uni`, no barriers, x-ring, h16 global
//   write-through). Waves 2/3 pre-stage sWo/sb/sEexp. One __syncthreads
//   (drains vmcnt -> h16 stores complete, L2-hot for phase 2).
// Phase 2+: verified pgs body (proj -> em3L in LDS; gold -> sgold; 32-chunk
//   scan -> Pst aliasing uni; alpha sweep in LDS) -> parts[b].
// Tail: last-block-done atomic: block 127-to-finish reduces parts with the
//   exact combine2 tree, writes out[0], resets cnt.
// ---------------------------------------------------------------------------
__global__ __launch_bounds__(256, 1) void mega_kernel(
    const _Float16* __restrict__ xgh, const float* __restrict__ Whh_f,
    const float* __restrict__ Whh_bb, _Float16* __restrict__ h16,
    const float* __restrict__ W_out, const float* __restrict__ b_out,
    const int* __restrict__ tags, const float* __restrict__ startv,
    const float* __restrict__ endv, const float* __restrict__ trans,
    float* __restrict__ parts, unsigned* __restrict__ cnt,
    float* __restrict__ out)
{
    __shared__ __align__(16) unsigned uni[16384];       // 64 KB: ph1 wlds[2][8192]; ph2 tile/Pst
    __shared__ __align__(16) float em3L[SB * 12];       // 24.6 KB
    __shared__ __align__(16) unsigned sWo[9 * 64];
    __shared__ float sb[9];
    __shared__ float sEexp[81];
    __shared__ __align__(16) _Float16 hbuf2[2][64];
    __shared__ float sgold;
    __shared__ int sflag;
    __shared__ float sm2[2];
    const int b = blockIdx.x, tid = threadIdx.x;

    if (tid < 128) {
        // ---- phase 1: frozen round-0 recurrence, wave = dir ----
        const int dir = tid >> 6;
        const int j = tid & 63;
        unsigned* wlds = &uni[dir * 8192];
        {   // stage dir-weights global floats -> f16 LDS (single wave, no barrier)
            const float* Wsrc = dir ? Whh_bb : Whh_f;
            uint4* dst = (uint4*)wlds;
            #pragma unroll
            for (int i = 0; i < 32; ++i) {
                int g = i >> 3, k4 = i & 7;
                const float* rp = Wsrc + (g * 64 + j) * 64 + 8 * k4;
                float4 f0 = *(const float4*)rp;
                float4 f1 = *(const float4*)(rp + 4);
                UF pack;
                pack.f[0] = (_Float16)f0.x; pack.f[1] = (_Float16)f0.y;
                pack.f[2] = (_Float16)f0.z; pack.f[3] = (_Float16)f0.w;
                pack.f[4] = (_Float16)f1.x; pack.f[5] = (_Float16)f1.y;
                pack.f[6] = (_Float16)f1.z; pack.f[7] = (_Float16)f1.w;
                dst[i * 64 + j] = pack.u;
            }
        }
        hbuf2[dir][j] = (_Float16)0.f;
        float c = 0.f;

        const int t0 = dir ? (SB - 1) : 0;
        const ptrdiff_t xstride = (dir ? -1 : 1) * (ptrdiff_t)(NB * 512);
        const _Float16* xp = xgh + ((size_t)(t0 * NB + b)) * 512 + dir * 256 + j * 4;
        _Float16* hp = h16 + ((size_t)(b * 2 + dir) * SB + t0) * 64 + j;
        const ptrdiff_t hstride = (dir ? -1 : 1) * (ptrdiff_t)64;

        U2 p0, p1, p2;
        p0.u = *(const uint2*)xp;
        p1.u = *(const uint2*)(xp + xstride);
        p2.u = *(const uint2*)(xp + 2 * xstride);
        const _Float16* xq = xp + 3 * xstride;

        const uint4* wl = (const uint4*)wlds;
        _Float16* hb = &hbuf2[dir][0];

        for (int s = 0; s < SB; ++s) {
            float a0 = (float)p0.f[0], a1 = (float)p0.f[1];
            float a2 = (float)p0.f[2], a3 = (float)p0.f[3];
            p0 = p1; p1 = p2;
            p2.u = *(const uint2*)xq;       // 3-deep; overruns land in adjacent ws slack
            xq += xstride;

            U4 hv[8];
            #pragma unroll
            for (int k4 = 0; k4 < 8; ++k4) hv[k4].u = *(const uint4*)&hb[k4 * 8];

            float g0[4] = {a0, 0.f, 0.f, 0.f};
            float g1[4] = {a1, 0.f, 0.f, 0.f};
            float g2[4] = {a2, 0.f, 0.f, 0.f};
            float g3[4] = {a3, 0.f, 0.f, 0.f};
            #pragma unroll
            for (int k4 = 0; k4 < 8; ++k4) {
                U4 w0, w1, w2, w3;
                w0.u = wl[(0 * 8 + k4) * 64 + j];
                w1.u = wl[(1 * 8 + k4) * 64 + j];
                w2.u = wl[(2 * 8 + k4) * 64 + j];
                w3.u = wl[(3 * 8 + k4) * 64 + j];
                const int p = k4 & 3;
                #pragma unroll
                for (int q = 0; q < 4; ++q) {
                    g0[p] = fdot2(hv[k4].h[q], w0.h[q], g0[p]);
                    g1[p] = fdot2(hv[k4].h[q], w1.h[q], g1[p]);
                    g2[p] = fdot2(hv[k4].h[q], w2.h[q], g2[p]);
                    g3[p] = fdot2(hv[k4].h[q], w3.h[q], g3[p]);
                }
            }
            a0 = (g0[0] + g0[1]) + (g0[2] + g0[3]);
            a1 = (g1[0] + g1[1]) + (g1[2] + g1[3]);
            a2 = (g2[0] + g2[1]) + (g2[2] + g2[3]);
            a3 = (g3[0] + g3[1]) + (g3[2] + g3[3]);

            float ig = fsig(a0), fg = fsig(a1), gg = ftanh(a2), og = fsig(a3);
            c = fg * c + ig * gg;
            float h = og * ftanh(c);
            *hp = (_Float16)h;
            hp += hstride;
            hb[j] = (_Float16)h;            // next iter's ds_reads ordered by lgkmcnt
        }
    } else {
        // ---- waves 2/3: pre-stage proj weights + exp(trans) ----
        for (int i2 = tid - 128; i2 < 576; i2 += 128) {
            int k = i2 >> 6, jp = i2 & 63;
            const float* src = W_out + (k + 1) * 128 + 2 * jp;
            UH u; u.f[0] = (_Float16)src[0]; u.f[1] = (_Float16)src[1];
            sWo[i2] = u.u;
        }
        if (tid - 128 < 9) sb[tid - 128] = b_out[1 + tid - 128];
        if (tid - 128 < 81) sEexp[tid - 128] = __expf(trans[tid - 128]);
    }
    __syncthreads();    // recurrence done, h16 stores drained (vmcnt), wlds dead

    // ---- phase 2: projection -> em3L (tile aliases uni) ----
    unsigned* tile = uni;
    float* Pst = (float*)uni;               // [32][84] alias, live after proj

    for (int tt = 0; tt < 4; ++tt) {
        const int t0 = tt * 128;
        __syncthreads();
        #pragma unroll
        for (int dir = 0; dir < 2; ++dir) {
            const unsigned* src = (const unsigned*)(h16 + ((size_t)(b * 2 + dir) * SB + t0) * 64);
            for (int i = tid; i < 4096; i += 256) {
                int t = i >> 5, jp = i & 31;
                tile[t * 64 + dir * 32 + jp] = src[i];
            }
        }
        __syncthreads();

        for (int o = tid; o < 1152; o += 256) {
            int tl = o / 9, k = o - 9 * tl;
            const U4* hr = (const U4*)&tile[tl * 64];
            const U4* wr = (const U4*)&sWo[k * 64];
            float pa = 0.f, pb = 0.f;
            #pragma unroll
            for (int qq = 0; qq < 16; qq += 2) {
                U4 hv = hr[qq], wv = wr[qq];
                U4 hv2 = hr[qq + 1], wv2 = wr[qq + 1];
                #pragma unroll
                for (int z = 0; z < 4; ++z) {
                    pa = fdot2(hv.h[z], wv.h[z], pa);
                    pb = fdot2(hv2.h[z], wv2.h[z], pb);
                }
            }
            em3L[(t0 + tl) * 12 + k] = pa + pb + sb[k];
        }
    }
    __syncthreads();    // em3L complete; tile free from here (Pst alias)

    if (tid >= 64 && tid < 128) {           // wave 1: gold-path score -> sgold
        const int l = tid - 64;
        const int* tb = tags + (size_t)b * SB;
        float sc = 0.f;
        for (int t = l; t < SB; t += 64) {
            int tg = tb[t] - 1;
            if (t > 0) {
                int tp = tb[t - 1] - 1;
                sc += trans[tp * 9 + tg] + em3L[t * 12 + tg];
            }
        }
        if (l == 0) {
            int tg0 = tb[0] - 1, tgl = tb[SB - 1] - 1;
            sc += startv[tg0] + em3L[tg0] + endv[tgl];
        }
        #pragma unroll
        for (int off = 32; off > 0; off >>= 1) sc += __shfl_down(sc, off);
        if (l == 0) sgold = sc;
    }

    if (tid < 32) {                         // wave 0: 32 parallel scan chunks -> Pst
        const int c = tid;
        float E[81];
        #pragma unroll
        for (int i = 0; i < 81; ++i) E[i] = sEexp[i];

        float P[81];
        #pragma unroll
        for (int i = 0; i < 81; ++i) P[i] = 0.f;
        #pragma unroll
        for (int i = 0; i < 9; ++i) P[i * 9 + i] = 1.f;
        float M = 0.f;

        const int t0 = 1 + 16 * c;
        const int nst = (t0 + 16 <= SB) ? 16 : (SB - t0);
        const float* ep = &em3L[t0 * 12];

        for (int s = 0; s < nst; ++s, ep += 12) {
            float4 e0 = *(const float4*)ep;
            float4 e1 = *(const float4*)(ep + 4);
            float e8 = ep[8];
            float ex[9] = { __expf(e0.x), __expf(e0.y), __expf(e0.z), __expf(e0.w),
                            __expf(e1.x), __expf(e1.y), __expf(e1.z), __expf(e1.w),
                            __expf(e8) };
            #pragma unroll
            for (int i = 0; i < 9; ++i) {
                float tmp[9];
                #pragma unroll
                for (int jj = 0; jj < 9; ++jj) tmp[jj] = P[i * 9] * E[jj];
                #pragma unroll
                for (int k = 1; k < 9; ++k)
                    #pragma unroll
                    for (int jj = 0; jj < 9; ++jj) tmp[jj] += P[i * 9 + k] * E[k * 9 + jj];
                #pragma unroll
                for (int jj = 0; jj < 9; ++jj) P[i * 9 + jj] = tmp[jj] * ex[jj];
            }
            if ((s & 3) == 3) {
                float mx = P[0];
                #pragma unroll
                for (int i = 1; i < 81; ++i) mx = fmaxf(mx, P[i]);
                M += __logf(mx);
                float r = frcp(mx);
                #pragma unroll
                for (int i = 0; i < 81; ++i) P[i] *= r;
            }
        }

        float* dst = &Pst[c * 84];
        #pragma unroll
        for (int i = 0; i < 81; ++i) dst[i] = P[i];
        dst[81] = M;
    }
    __syncthreads();    // Pst + sgold ready

    float part = 0.f;
    if (tid < 64) {                         // alpha sweep in LDS (combine body)
        float A[9], M = 0.f;
        #pragma unroll
        for (int k = 0; k < 9; ++k) A[k] = __expf(startv[k] + em3L[k]);

        for (int c = 0; c < 32; ++c) {
            const float4* src = (const float4*)&Pst[c * 84];
            float buf[84];
            #pragma unroll
            for (int qq = 0; qq < 21; ++qq) {
                float4 v = src[qq];
                buf[4 * qq] = v.x; buf[4 * qq + 1] = v.y; buf[4 * qq + 2] = v.z; buf[4 * qq + 3] = v.w;
            }
            float tmp[9];
            #pragma unroll
            for (int jj = 0; jj < 9; ++jj) tmp[jj] = A[0] * buf[jj];
            #pragma unroll
            for (int i = 1; i < 9; ++i)
                #pragma unroll
                for (int jj = 0; jj < 9; ++jj) tmp[jj] += A[i] * buf[i * 9 + jj];
            float mx = tmp[0];
            #pragma unroll
            for (int jj = 1; jj < 9; ++jj) mx = fmaxf(mx, tmp[jj]);
            M += __logf(mx) + buf[81];
            float r = frcp(mx);
            #pragma unroll
            for (int jj = 0; jj < 9; ++jj) A[jj] = tmp[jj] * r;
        }

        float Z = 0.f;
        #pragma unroll
        for (int k = 0; k < 9; ++k) Z += A[k] * __expf(endv[k]);
        part = M + __logf(Z) - sgold;
    }

    // ---- tail: publish + last-block-done reduction (replaces combine2) ----
    if (tid == 0) {
        atomicExch(&parts[b], part);        // device-coherent store
        __threadfence();
        unsigned old = atomicAdd(cnt, 1u);
        sflag = (old == NB - 1) ? 1 : 0;
    }
    __syncthreads();
    if (sflag) {
        float v = 0.f;
        if (tid < NB) v = atomicAdd(&parts[tid], 0.0f);   // device-coherent read
        #pragma unroll
        for (int off = 32; off > 0; off >>= 1) v += __shfl_down(v, off);
        if (tid < NB && (tid & 63) == 0) sm2[tid >> 6] = v;
        __syncthreads();
        if (tid == 0) {
            out[0] = (sm2[0] + sm2[1]) * (1.0f / NB);
            atomicExch(cnt, 0u);            // reset for next replay (belt & braces)
        }
    }
}

extern "C" void kernel_launch(void* const* d_in, const int* in_sizes, int n_in,
                              void* d_out, int out_size, void* d_ws, size_t ws_size,
                              hipStream_t stream)
{
    const int*   inputs = (const int*)d_in[0];
    const int*   tags   = (const int*)d_in[1];
    // d_in[2] = mask: all-true, unused
    const float* emb    = (const float*)d_in[3];
    const float* Wih_f  = (const float*)d_in[4];
    const float* Whh_f  = (const float*)d_in[5];
    const float* b_f    = (const float*)d_in[6];
    const float* Wih_b  = (const float*)d_in[7];
    const float* Whh_b  = (const float*)d_in[8];
    const float* b_b    = (const float*)d_in[9];
    const float* W_out  = (const float*)d_in[10];
    const float* b_out  = (const float*)d_in[11];
    const float* startv = (const float*)d_in[12];
    const float* endv   = (const float*)d_in[13];
    const float* transv = (const float*)d_in[14];

    char* w = (char*)d_ws;
    float* parts   = (float*)w;
    unsigned* cnt  = (unsigned*)(w + NB * 4);
    w += (size_t)NB * SB * 12 * 4;    // 3.1 MB region: parts+cnt use <1 KB,
                                      // rest = pre-slack for lstm dir=1 x-ring underrun
    _Float16* xgh  = (_Float16*)w;  w += (size_t)SB * NB * 512 * 2;   // 67.1 MB
    _Float16* h16  = (_Float16*)w;  w += (size_t)NB * 2 * SB * 64 * 2;// 16.8 MB (post-slack for dir=0 x-ring overrun)
    (void)w;

    gemm_kernel<<<SB, 256, 0, stream>>>(inputs, emb, Wih_f, Wih_b, b_f, b_b, xgh, cnt);
    mega_kernel<<<NB, 256, 0, stream>>>(xgh, Whh_f, Whh_b, h16, W_out, b_out, tags,
                                        startv, endv, transv, parts, cnt, (float*)d_out);
}

// Round 11
// 445.356 us; speedup vs baseline: 1.3272x; 1.0097x over previous
//
#include <hip/hip_runtime.h>
#include <math.h>

#define SB 512
#define NB 128
#define HD 64

typedef _Float16 h2 __attribute__((ext_vector_type(2)));
typedef _Float16 f16x8 __attribute__((ext_vector_type(8)));
typedef float f32x4 __attribute__((ext_vector_type(4)));
union U4 { uint4 u; h2 h[4]; _Float16 f[8]; };
union UF { uint4 u; f16x8 h8; _Float16 f[8]; };
union U2 { uint2 u; _Float16 f[4]; };
union UH { unsigned u; _Float16 f[2]; };

__device__ __forceinline__ float frcp(float x) { return __builtin_amdgcn_rcpf(x); }
__device__ __forceinline__ float fsig(float x) { return frcp(1.0f + __expf(-x)); }
__device__ __forceinline__ float ftanh(float x) {
    float t = __expf(-2.0f * fabsf(x));
    float r = (1.0f - t) * frcp(1.0f + t);
    return copysignf(r, x);
}
__device__ __forceinline__ float fdot2(h2 a, h2 b, float c) {
    return __builtin_amdgcn_fdot2(a, b, c, false);
}

// ---------------------------------------------------------------------------
// input GEMM, MFMA, bank-fixed (rounds 8/9/10 verified; adds flags/cnt reset).
// ---------------------------------------------------------------------------
__global__ __launch_bounds__(256, 2) void gemm_kernel(
    const int* __restrict__ inputs, const float* __restrict__ emb,
    const float* __restrict__ Wih_f, const float* __restrict__ Wih_bb,
    const float* __restrict__ b_f, const float* __restrict__ b_bb,
    _Float16* __restrict__ xgh, unsigned* __restrict__ cnt,
    unsigned* __restrict__ flags)
{
    __shared__ __align__(16) unsigned sE[128 * 68];   // 34.8 KB
    __shared__ __align__(16) unsigned sW[128 * 68];   // 34.8 KB
    __shared__ float sbias[512];
    __shared__ int stok[128];
    const int tt = blockIdx.x;
    const int tid = threadIdx.x;
    const int w = tid >> 6, l = tid & 63;
    const int q = l >> 4, n = l & 15;

    if (tt == 0) {                        // reset handoff state each replay
        if (tid == 0) *cnt = 0u;
        if (tid < 256) flags[tid] = 0u;
    }

    if (tid < 128) stok[tid] = inputs[tid * SB + tt];
    for (int i = tid; i < 512; i += 256) {
        int dir = i >> 8, r = i & 255, jj = r >> 2, g = r & 3;
        sbias[i] = (dir ? b_bb : b_f)[g * 64 + jj];
    }
    __syncthreads();
    for (int idx = tid; idx < 8192; idx += 256) {
        int row = idx >> 6, d = idx & 63;
        unsigned v = 0;
        if (d < 50) {
            const float* ep = emb + (size_t)stok[row] * 100 + 2 * d;
            UH u; u.f[0] = (_Float16)ep[0]; u.f[1] = (_Float16)ep[1];
            v = u.u;
        }
        sE[row * 68 + d] = v;
    }

    for (int cg = 0; cg < 4; ++cg) {
        __syncthreads();                      // sE ready / sW safe to overwrite
        for (int idx = tid; idx < 2048; idx += 256) {
            int col = cg * 128 + (idx >> 4);
            int dir = col >> 8, r = col & 255, jj = r >> 2, g = r & 3;
            const float* base = (dir ? Wih_bb : Wih_f) + (g * 64 + jj) * 100;
            int dq = idx & 15;                // halves d = 4dq..4dq+3 = floats 8dq..8dq+7
            UF pack; pack.u = make_uint4(0, 0, 0, 0);
            if (dq < 12) {
                float4 f0 = *(const float4*)(base + 8 * dq);
                float4 f1 = *(const float4*)(base + 8 * dq + 4);
                pack.f[0] = (_Float16)f0.x; pack.f[1] = (_Float16)f0.y;
                pack.f[2] = (_Float16)f0.z; pack.f[3] = (_Float16)f0.w;
                pack.f[4] = (_Float16)f1.x; pack.f[5] = (_Float16)f1.y;
                pack.f[6] = (_Float16)f1.z; pack.f[7] = (_Float16)f1.w;
            } else if (dq == 12) {            // floats 96..99 valid, 100..103 pad
                float4 f0 = *(const float4*)(base + 96);
                pack.f[0] = (_Float16)f0.x; pack.f[1] = (_Float16)f0.y;
                pack.f[2] = (_Float16)f0.z; pack.f[3] = (_Float16)f0.w;
            }
            ((uint4*)sW)[(idx >> 4) * 17 + dq] = pack.u;
        }
        __syncthreads();

        f32x4 acc[2][8];
        #pragma unroll
        for (int m = 0; m < 2; ++m)
            #pragma unroll
            for (int c = 0; c < 8; ++c)
                #pragma unroll
                for (int r = 0; r < 4; ++r) acc[m][c][r] = 0.f;

        #pragma unroll
        for (int kt = 0; kt < 4; ++kt) {
            const int ko = 16 * kt + 2 * q;
            UF A0, A1;
            {
                const unsigned* rp = &sE[(16 * (2 * w + 0) + n) * 68 + ko];
                uint2 lo = *(const uint2*)rp;
                uint2 hi = *(const uint2*)(rp + 8);
                A0.u = make_uint4(lo.x, lo.y, hi.x, hi.y);
                rp = &sE[(16 * (2 * w + 1) + n) * 68 + ko];
                lo = *(const uint2*)rp;
                hi = *(const uint2*)(rp + 8);
                A1.u = make_uint4(lo.x, lo.y, hi.x, hi.y);
            }
            UF B[8];
            #pragma unroll
            for (int c = 0; c < 8; ++c) {
                const unsigned* rp = &sW[(16 * c + n) * 68 + ko];
                uint2 lo = *(const uint2*)rp;
                uint2 hi = *(const uint2*)(rp + 8);
                B[c].u = make_uint4(lo.x, lo.y, hi.x, hi.y);
            }
            #pragma unroll
            for (int c = 0; c < 8; ++c) {
                acc[0][c] = __builtin_amdgcn_mfma_f32_16x16x32_f16(A0.h8, B[c].h8, acc[0][c], 0, 0, 0);
                acc[1][c] = __builtin_amdgcn_mfma_f32_16x16x32_f16(A1.h8, B[c].h8, acc[1][c], 0, 0, 0);
            }
        }

        #pragma unroll
        for (int m = 0; m < 2; ++m)
            #pragma unroll
            for (int c = 0; c < 8; ++c) {
                int col = cg * 128 + 16 * c + n;
                float bc = sbias[col];
                #pragma unroll
                for (int r = 0; r < 4; ++r) {
                    int row = 16 * (2 * w + m) + 4 * q + r;   // batch index
                    xgh[(size_t)(tt * NB + row) * 512 + col] = (_Float16)(acc[m][c][r] + bc);
                }
            }
    }
}

// ---------------------------------------------------------------------------
// MEGAKERNEL v2: 256 blocks x 256 threads, LDS 93 KB -> 1 block/CU -> all 256
// blocks co-resident, each lstm stream on its OWN CU (round-10's 2-waves/CU
// LDS-pipe contention removed; phase 1 is cycle-identical to the frozen
// 218-us standalone). Block blk: stream (b=blk&127, dir=blk>>7) on wave 0;
// waves 1-3 prestage sWo/sb/sEexp. Handoff: syncthreads (vmcnt drain) ->
// threadfence (L2 writeback, cross-XCD) -> atomicExch(flags[blk]). Blocks
// >=128 exit; block b polls flags[b+128] (device-scope atomic + acquire
// fence), then runs the verified pgs body (tile/sWo rows padded 64->68 dwords
// to kill proj bank conflicts) + last-block reduction tail.
// ---------------------------------------------------------------------------
__global__ __launch_bounds__(256, 1) void mega_kernel(
    const _Float16* __restrict__ xgh, const float* __restrict__ Whh_f,
    const float* __restrict__ Whh_bb, _Float16* __restrict__ h16,
    const float* __restrict__ W_out, const float* __restrict__ b_out,
    const int* __restrict__ tags, const float* __restrict__ startv,
    const float* __restrict__ endv, const float* __restrict__ trans,
    float* __restrict__ parts, unsigned* __restrict__ cnt,
    unsigned* __restrict__ flags, float* __restrict__ out)
{
    __shared__ __align__(16) unsigned uni[16384];       // 64 KB: ph1 wlds (first 32 KB); ph2 tile[128*68]/Pst
    __shared__ __align__(16) float em3L[SB * 12];       // 24.6 KB
    __shared__ __align__(16) unsigned sWo[9 * 68];      // padded rows (bank spread)
    __shared__ float sb[9];
    __shared__ float sEexp[81];
    __shared__ __align__(16) _Float16 hbuf[64];
    __shared__ float sgold;
    __shared__ int sflag;
    __shared__ float sm2[2];
    const int blk = blockIdx.x, tid = threadIdx.x;
    const int b = blk & (NB - 1);
    const int dir = blk >> 7;

    if (tid < 64) {
        // ---- phase 1: frozen round-0 recurrence, 1 wave, private CU ----
        const int j = tid;
        unsigned* wlds = uni;
        {   // stage dir-weights global floats -> f16 LDS (single wave, no barrier)
            const float* Wsrc = dir ? Whh_bb : Whh_f;
            uint4* dst = (uint4*)wlds;
            #pragma unroll
            for (int i = 0; i < 32; ++i) {
                int g = i >> 3, k4 = i & 7;
                const float* rp = Wsrc + (g * 64 + j) * 64 + 8 * k4;
                float4 f0 = *(const float4*)rp;
                float4 f1 = *(const float4*)(rp + 4);
                UF pack;
                pack.f[0] = (_Float16)f0.x; pack.f[1] = (_Float16)f0.y;
                pack.f[2] = (_Float16)f0.z; pack.f[3] = (_Float16)f0.w;
                pack.f[4] = (_Float16)f1.x; pack.f[5] = (_Float16)f1.y;
                pack.f[6] = (_Float16)f1.z; pack.f[7] = (_Float16)f1.w;
                dst[i * 64 + j] = pack.u;
            }
        }
        hbuf[j] = (_Float16)0.f;
        float c = 0.f;

        const int t0 = dir ? (SB - 1) : 0;
        const ptrdiff_t xstride = (dir ? -1 : 1) * (ptrdiff_t)(NB * 512);
        const _Float16* xp = xgh + ((size_t)(t0 * NB + b)) * 512 + dir * 256 + j * 4;
        _Float16* hp = h16 + ((size_t)(b * 2 + dir) * SB + t0) * 64 + j;
        const ptrdiff_t hstride = (dir ? -1 : 1) * (ptrdiff_t)64;

        U2 p0, p1, p2;
        p0.u = *(const uint2*)xp;
        p1.u = *(const uint2*)(xp + xstride);
        p2.u = *(const uint2*)(xp + 2 * xstride);
        const _Float16* xq = xp + 3 * xstride;

        const uint4* wl = (const uint4*)wlds;

        for (int s = 0; s < SB; ++s) {
            float a0 = (float)p0.f[0], a1 = (float)p0.f[1];
            float a2 = (float)p0.f[2], a3 = (float)p0.f[3];
            p0 = p1; p1 = p2;
            p2.u = *(const uint2*)xq;       // 3-deep; overruns land in adjacent ws slack
            xq += xstride;

            U4 hv[8];
            #pragma unroll
            for (int k4 = 0; k4 < 8; ++k4) hv[k4].u = *(const uint4*)&hbuf[k4 * 8];

            float g0[4] = {a0, 0.f, 0.f, 0.f};
            float g1[4] = {a1, 0.f, 0.f, 0.f};
            float g2[4] = {a2, 0.f, 0.f, 0.f};
            float g3[4] = {a3, 0.f, 0.f, 0.f};
            #pragma unroll
            for (int k4 = 0; k4 < 8; ++k4) {
                U4 w0, w1, w2, w3;
                w0.u = wl[(0 * 8 + k4) * 64 + j];
                w1.u = wl[(1 * 8 + k4) * 64 + j];
                w2.u = wl[(2 * 8 + k4) * 64 + j];
                w3.u = wl[(3 * 8 + k4) * 64 + j];
                const int p = k4 & 3;
                #pragma unroll
                for (int q = 0; q < 4; ++q) {
                    g0[p] = fdot2(hv[k4].h[q], w0.h[q], g0[p]);
                    g1[p] = fdot2(hv[k4].h[q], w1.h[q], g1[p]);
                    g2[p] = fdot2(hv[k4].h[q], w2.h[q], g2[p]);
                    g3[p] = fdot2(hv[k4].h[q], w3.h[q], g3[p]);
                }
            }
            a0 = (g0[0] + g0[1]) + (g0[2] + g0[3]);
            a1 = (g1[0] + g1[1]) + (g1[2] + g1[3]);
            a2 = (g2[0] + g2[1]) + (g2[2] + g2[3]);
            a3 = (g3[0] + g3[1]) + (g3[2] + g3[3]);

            float ig = fsig(a0), fg = fsig(a1), gg = ftanh(a2), og = fsig(a3);
            c = fg * c + ig * gg;
            float h = og * ftanh(c);
            *hp = (_Float16)h;
            hp += hstride;
            hbuf[j] = (_Float16)h;          // next iter's ds_reads ordered by lgkmcnt
        }
    } else {
        // ---- waves 1-3: prestage proj weights + exp(trans) ----
        for (int i2 = tid - 64; i2 < 576; i2 += 192) {
            int k = i2 >> 6, jp = i2 & 63;
            const float* src = W_out + (k + 1) * 128 + 2 * jp;
            UH u; u.f[0] = (_Float16)src[0]; u.f[1] = (_Float16)src[1];
            sWo[k * 68 + jp] = u.u;
        }
        if (tid - 64 < 9) sb[tid - 64] = b_out[1 + tid - 64];
        if (tid - 64 < 81) sEexp[tid - 64] = __expf(trans[tid - 64]);
    }
    __syncthreads();    // wave-0 h16 stores drained (vmcnt) at this barrier

    if (tid == 0) {
        __threadfence();                    // publish h16 across XCDs (L2 wb)
        atomicExch(&flags[blk], 1u);        // release
    }
    if (blk >= NB) return;                  // dir-1 blocks done

    if (tid == 0) {
        while (atomicAdd(&flags[b + NB], 0u) == 0u)
            __builtin_amdgcn_s_sleep(16);
        __threadfence();                    // acquire: invalidate stale caches
    }
    __syncthreads();

    // ---- phase 2: projection -> em3L (tile aliases uni; rows 68 dwords) ----
    unsigned* tile = uni;
    float* Pst = (float*)uni;               // [32][84] alias, live after proj

    for (int tt = 0; tt < 4; ++tt) {
        const int t0 = tt * 128;
        __syncthreads();
        #pragma unroll
        for (int dd = 0; dd < 2; ++dd) {
            const unsigned* src = (const unsigned*)(h16 + ((size_t)(b * 2 + dd) * SB + t0) * 64);
            for (int i = tid; i < 4096; i += 256) {
                int t = i >> 5, jp = i & 31;
                tile[t * 68 + dd * 32 + jp] = src[i];
            }
        }
        __syncthreads();

        for (int o = tid; o < 1152; o += 256) {
            int tl = o / 9, k = o - 9 * tl;
            const U4* hr = (const U4*)&tile[tl * 68];
            const U4* wr = (const U4*)&sWo[k * 68];
            float pa = 0.f, pb = 0.f;
            #pragma unroll
            for (int qq = 0; qq < 16; qq += 2) {
                U4 hv = hr[qq], wv = wr[qq];
                U4 hv2 = hr[qq + 1], wv2 = wr[qq + 1];
                #pragma unroll
                for (int z = 0; z < 4; ++z) {
                    pa = fdot2(hv.h[z], wv.h[z], pa);
                    pb = fdot2(hv2.h[z], wv2.h[z], pb);
                }
            }
            em3L[(t0 + tl) * 12 + k] = pa + pb + sb[k];
        }
    }
    __syncthreads();    // em3L complete; tile free from here (Pst alias)

    if (tid >= 64 && tid < 128) {           // wave 1: gold-path score -> sgold
        const int l = tid - 64;
        const int* tb = tags + (size_t)b * SB;
        float sc = 0.f;
        for (int t = l; t < SB; t += 64) {
            int tg = tb[t] - 1;
            if (t > 0) {
                int tp = tb[t - 1] - 1;
                sc += trans[tp * 9 + tg] + em3L[t * 12 + tg];
            }
        }
        if (l == 0) {
            int tg0 = tb[0] - 1, tgl = tb[SB - 1] - 1;
            sc += startv[tg0] + em3L[tg0] + endv[tgl];
        }
        #pragma unroll
        for (int off = 32; off > 0; off >>= 1) sc += __shfl_down(sc, off);
        if (l == 0) sgold = sc;
    }

    if (tid < 32) {                         // wave 0: 32 parallel scan chunks -> Pst
        const int c = tid;
        float E[81];
        #pragma unroll
        for (int i = 0; i < 81; ++i) E[i] = sEexp[i];

        float P[81];
        #pragma unroll
        for (int i = 0; i < 81; ++i) P[i] = 0.f;
        #pragma unroll
        for (int i = 0; i < 9; ++i) P[i * 9 + i] = 1.f;
        float M = 0.f;

        const int t0 = 1 + 16 * c;
        const int nst = (t0 + 16 <= SB) ? 16 : (SB - t0);
        const float* ep = &em3L[t0 * 12];

        for (int s = 0; s < nst; ++s, ep += 12) {
            float4 e0 = *(const float4*)ep;
            float4 e1 = *(const float4*)(ep + 4);
            float e8 = ep[8];
            float ex[9] = { __expf(e0.x), __expf(e0.y), __expf(e0.z), __expf(e0.w),
                            __expf(e1.x), __expf(e1.y), __expf(e1.z), __expf(e1.w),
                            __expf(e8) };
            #pragma unroll
            for (int i = 0; i < 9; ++i) {
                float tmp[9];
                #pragma unroll
                for (int jj = 0; jj < 9; ++jj) tmp[jj] = P[i * 9] * E[jj];
                #pragma unroll
                for (int k = 1; k < 9; ++k)
                    #pragma unroll
                    for (int jj = 0; jj < 9; ++jj) tmp[jj] += P[i * 9 + k] * E[k * 9 + jj];
                #pragma unroll
                for (int jj = 0; jj < 9; ++jj) P[i * 9 + jj] = tmp[jj] * ex[jj];
            }
            if ((s & 3) == 3) {
                float mx = P[0];
                #pragma unroll
                for (int i = 1; i < 81; ++i) mx = fmaxf(mx, P[i]);
                M += __logf(mx);
                float r = frcp(mx);
                #pragma unroll
                for (int i = 0; i < 81; ++i) P[i] *= r;
            }
        }

        float* dst = &Pst[c * 84];
        #pragma unroll
        for (int i = 0; i < 81; ++i) dst[i] = P[i];
        dst[81] = M;
    }
    __syncthreads();    // Pst + sgold ready

    float part = 0.f;
    if (tid < 64) {                         // alpha sweep in LDS (combine body)
        float A[9], M = 0.f;
        #pragma unroll
        for (int k = 0; k < 9; ++k) A[k] = __expf(startv[k] + em3L[k]);

        for (int c = 0; c < 32; ++c) {
            const float4* src = (const float4*)&Pst[c * 84];
            float buf[84];
            #pragma unroll
            for (int qq = 0; qq < 21; ++qq) {
                float4 v = src[qq];
                buf[4 * qq] = v.x; buf[4 * qq + 1] = v.y; buf[4 * qq + 2] = v.z; buf[4 * qq + 3] = v.w;
            }
            float tmp[9];
            #pragma unroll
            for (int jj = 0; jj < 9; ++jj) tmp[jj] = A[0] * buf[jj];
            #pragma unroll
            for (int i = 1; i < 9; ++i)
                #pragma unroll
                for (int jj = 0; jj < 9; ++jj) tmp[jj] += A[i] * buf[i * 9 + jj];
            float mx = tmp[0];
            #pragma unroll
            for (int jj = 1; jj < 9; ++jj) mx = fmaxf(mx, tmp[jj]);
            M += __logf(mx) + buf[81];
            float r = frcp(mx);
            #pragma unroll
            for (int jj = 0; jj < 9; ++jj) A[jj] = tmp[jj] * r;
        }

        float Z = 0.f;
        #pragma unroll
        for (int k = 0; k < 9; ++k) Z += A[k] * __expf(endv[k]);
        part = M + __logf(Z) - sgold;
    }

    // ---- tail: publish + last-block-done reduction (NB arrivals) ----
    if (tid == 0) {
        atomicExch(&parts[b], part);        // device-coherent store
        __threadfence();
        unsigned old = atomicAdd(cnt, 1u);
        sflag = (old == NB - 1) ? 1 : 0;
    }
    __syncthreads();
    if (sflag) {
        float v = 0.f;
        if (tid < NB) v = atomicAdd(&parts[tid], 0.0f);   // device-coherent read
        #pragma unroll
        for (int off = 32; off > 0; off >>= 1) v += __shfl_down(v, off);
        if (tid < NB && (tid & 63) == 0) sm2[tid >> 6] = v;
        __syncthreads();
        if (tid == 0) {
            out[0] = (sm2[0] + sm2[1]) * (1.0f / NB);
            atomicExch(cnt, 0u);            // reset for next replay (belt & braces)
        }
    }
}

extern "C" void kernel_launch(void* const* d_in, const int* in_sizes, int n_in,
                              void* d_out, int out_size, void* d_ws, size_t ws_size,
                              hipStream_t stream)
{
    const int*   inputs = (const int*)d_in[0];
    const int*   tags   = (const int*)d_in[1];
    // d_in[2] = mask: all-true, unused
    const float* emb    = (const float*)d_in[3];
    const float* Wih_f  = (const float*)d_in[4];
    const float* Whh_f  = (const float*)d_in[5];
    const float* b_f    = (const float*)d_in[6];
    const float* Wih_b  = (const float*)d_in[7];
    const float* Whh_b  = (const float*)d_in[8];
    const float* b_b    = (const float*)d_in[9];
    const float* W_out  = (const float*)d_in[10];
    const float* b_out  = (const float*)d_in[11];
    const float* startv = (const float*)d_in[12];
    const float* endv   = (const float*)d_in[13];
    const float* transv = (const float*)d_in[14];

    char* w = (char*)d_ws;
    float* parts   = (float*)w;                       // 512 B
    unsigned* cnt  = (unsigned*)(w + NB * 4);         // 4 B
    unsigned* flags= (unsigned*)(w + NB * 4 + 256);   // 1 KB (aligned region)
    w += (size_t)NB * SB * 12 * 4;    // 3.1 MB region: control uses <2 KB,
                                      // rest = pre-slack for lstm dir=1 x-ring underrun (<=786 KB)
    _Float16* xgh  = (_Float16*)w;  w += (size_t)SB * NB * 512 * 2;   // 67.1 MB
    _Float16* h16  = (_Float16*)w;  w += (size_t)NB * 2 * SB * 64 * 2;// 16.8 MB (post-slack for dir=0 x-ring overrun)
    (void)w;

    gemm_kernel<<<SB, 256, 0, stream>>>(inputs, emb, Wih_f, Wih_b, b_f, b_b, xgh, cnt, flags);
    mega_kernel<<<256, 256, 0, stream>>>(xgh, Whh_f, Whh_b, h16, W_out, b_out, tags,
                                         startv, endv, transv, parts, cnt, flags, (float*)d_out);
}